// Round 8
// baseline (578.330 us; speedup 1.0000x reference)
//
#include <hip/hip_runtime.h>
#include <math.h>

// DCGRU cell, N=4096, B=32, U=64, F=66, M=5, 2 supports.
// R19: gate/cand restructured for weight-stationarity: 8 (gate) / 4 (cand)
// waves per block, each wave owns ONE output tile t and keeps its 11 B-frags
// (44 VGPRs) resident while looping G n's x 2 Mtiles. Wf broadcast traffic
// 737MB -> 46MB (was re-read per block: 180KB x 4096). No LDS, no barriers;
// in-place xh' hazard removed by writing to bufA2 (gconv2+cand read bufA2).
// prep_w/extract_csr/build_x0 fused into one prologue dispatch (-2 launches).
// spmm untouched: R12 local optimum (73.4us, convergence-tested R13/R15/R16).

#define NN 4096
#define BB 32
#define UU 64
#define FF 66
#define MM 5
#define XHC 2048       // xh row elements (4096 B)
#define XIC 64         // xi row elements (128 B)
#define CAP 128        // max nnz/row, padded to %8 (min 16)
#define CHUNK 4
#define WF_G (8*11*64*8)
#define WF_C (4*11*64*8)
#define PW_BLK ((WF_G + WF_C + 255) / 256)   // 264

typedef unsigned short u16;
typedef __attribute__((ext_vector_type(8))) short short8;
typedef __attribute__((ext_vector_type(4))) float float4v;

__device__ __forceinline__ u16 f2bf(float f) {
  unsigned u = __float_as_uint(f);
  u += 0x7FFFu + ((u >> 16) & 1u);   // RNE
  return (u16)(u >> 16);
}
__device__ __forceinline__ unsigned pack2(float lo, float hi) {
  return (unsigned)f2bf(lo) | ((unsigned)f2bf(hi) << 16);
}
__device__ __forceinline__ float bflo(unsigned d) { return __uint_as_float(d << 16); }
__device__ __forceinline__ float bfhi(unsigned d) { return __uint_as_float(d & 0xFFFF0000u); }
__device__ __forceinline__ float bf1(u16 v) { return __uint_as_float((unsigned)v << 16); }

__device__ __forceinline__ float sigmoidf_(float x) {
  return 1.0f / (1.0f + __expf(-x));
}
__device__ __forceinline__ float tanhf_(float x) {
  x = fminf(fmaxf(x, -15.f), 15.f);
  float e = __expf(2.f * x);
  return (e - 1.f) / (e + 1.f);
}

// ---------------- weight fold helper ----------------------------------------
__device__ __forceinline__ float wfold(const float* W, int f, int m, int o, int O) {
  if (m == 0)
    return W[((size_t)f * MM + 0) * O + o] - W[((size_t)f * MM + 2) * O + o]
         - W[((size_t)f * MM + 4) * O + o];
  float v = W[((size_t)f * MM + m) * O + o];
  return (m == 2 || m == 4) ? 2.0f * v : v;
}

// ---------------- fused prologue: prep_w | extract_csr | build_x0 -----------
__global__ __launch_bounds__(256) void prologue(
    const float* __restrict__ W, const float* __restrict__ W2,
    u16* __restrict__ Wf, u16* __restrict__ W2f,
    const float* __restrict__ S0, const float* __restrict__ S1,
    int* __restrict__ cols, float* __restrict__ vals, int* __restrict__ nnz,
    const float* __restrict__ inp, const float* __restrict__ hx,
    u16* __restrict__ xi0, u16* __restrict__ xh0) {
  int bid = blockIdx.x;
  if (bid < PW_BLK) {
    // ---- prep_w: Chebyshev fold + k-scan fragment order ----
    int idx = bid * 256 + threadIdx.x;
    if (idx < WF_G) {
      int j = idx & 7, lane = (idx >> 3) & 63, q = idx >> 9;
      int ks = q % 11, t = q / 11;
      int o = t * 16 + (lane & 15);
      int qj = (lane >> 4) * 8 + j;
      float v = 0.f;
      if (ks < 10)      { v = wfold(W, 2 + (ks & 1) * 32 + qj, ks >> 1, o, 128); }
      else if (qj < 10) { v = wfold(W, qj & 1, qj >> 1, o, 128); }
      Wf[idx] = f2bf(v);
    } else if (idx < WF_G + WF_C) {
      int i2 = idx - WF_G;
      int j = i2 & 7, lane = (i2 >> 3) & 63, q = i2 >> 9;
      int ks = q % 11, t = q / 11;
      int o = t * 16 + (lane & 15);
      int qj = (lane >> 4) * 8 + j;
      float v = 0.f;
      if (ks < 10)      { v = wfold(W2, 2 + (ks & 1) * 32 + qj, ks >> 1, o, UU); }
      else if (qj < 10) { v = wfold(W2, qj & 1, qj >> 1, o, UU); }
      W2f[i2] = f2bf(v);
    }
  } else if (bid < PW_BLK + 2048) {
    // ---- extract_csr: rows zero-padded to %8, min 16 ----
    int e = bid - PW_BLK;
    int sup = e >> 10;
    int bx  = e & 1023;
    int wave = threadIdx.x >> 6;
    int lane = threadIdx.x & 63;
    int row  = bx * 4 + wave;
    const float* srow = (sup ? S1 : S0) + (size_t)row * NN;
    int*   crow = cols + ((size_t)sup * NN + row) * CAP;
    float* vrow = vals + ((size_t)sup * NN + row) * CAP;
    int base = 0;
    for (int j0 = 0; j0 < NN; j0 += 64) {
      float v = srow[j0 + lane];
      unsigned long long mask = __ballot(v != 0.0f);
      if (v != 0.0f) {
        int pos = base + __popcll(mask & ((1ull << lane) - 1ull));
        if (pos < CAP) { crow[pos] = j0 + lane; vrow[pos] = v; }
      }
      base += __popcll(mask);
    }
    if (base > CAP) base = CAP;
    int padded = (base + 7) & ~7;
    if (padded < 16) padded = 16;
    if (padded > CAP) padded = CAP;
    int p = base + lane;
    if (p < padded) { crow[p] = 0; vrow[p] = 0.0f; }
    if (lane == 0) nnz[sup * NN + row] = padded;
  } else {
    // ---- build_x0 ----
    int n = bid - PW_BLK - 2048;
    unsigned* xhd = (unsigned*)(xh0 + (size_t)n * XHC);
    for (int j = threadIdx.x; j < XHC / 2; j += 256) {
      int b = j >> 5, f2 = (j & 31) * 2;
      const float* h = hx + (size_t)b * (NN * UU) + (size_t)n * UU + f2;
      xhd[j] = pack2(h[0], h[1]);
    }
    if (threadIdx.x < 32) {
      int b = threadIdx.x;
      unsigned* xid = (unsigned*)(xi0 + (size_t)n * XIC);
      xid[b] = pack2(inp[(size_t)b * (NN * 2) + n * 2],
                     inp[(size_t)b * (NN * 2) + n * 2 + 1]);
    }
  }
}

// ---------------- SpMM: y = S@x. 4x1KB panels, VGPR gather, dbuf (R12) ------
__device__ __forceinline__ void fma8(float v, uint4 q, float* a) {
  a[0] = fmaf(v, bflo(q.x), a[0]); a[1] = fmaf(v, bfhi(q.x), a[1]);
  a[2] = fmaf(v, bflo(q.y), a[2]); a[3] = fmaf(v, bfhi(q.y), a[3]);
  a[4] = fmaf(v, bflo(q.z), a[4]); a[5] = fmaf(v, bfhi(q.z), a[5]);
  a[6] = fmaf(v, bflo(q.w), a[6]); a[7] = fmaf(v, bfhi(q.w), a[7]);
}

__device__ __forceinline__ void loadC4(uint4* q, const int* crow, int k0,
                                       const u16* gpan, int lane) {
#pragma unroll
  for (int i = 0; i < CHUNK; ++i) {
    int c = crow[k0 + i];                             // scalar (s_load)
    q[i] = *(const uint4*)(gpan + ((size_t)c << 11) + (lane << 3));
  }
}

__device__ __forceinline__ void fmaC(const uint4* q, const float* vv, float* a) {
#pragma unroll
  for (int i = 0; i < CHUNK; ++i) fma8(vv[i], q[i], a);
}

__global__ __launch_bounds__(128) void spmm_panel(
    const int* __restrict__ cols, const float* __restrict__ vals,
    const int* __restrict__ nnz,
    const u16* xiA, const u16* xhA, const u16* xiB, const u16* xhB,
    int sup_base,
    u16* yiA, u16* yhA, u16* yiB, u16* yhB) {
  int bx = blockIdx.x;
  int lane = threadIdx.x & 63;
  int wv = threadIdx.x >> 6;
  int sup = sup_base + blockIdx.y;

  if (bx < 8192) {
    int panel = bx & 3;
    int row = (bx >> 2) * 2 + wv;
    int srow = __builtin_amdgcn_readfirstlane(sup * NN + row);
    const u16* xh = blockIdx.y ? xhB : xhA;
    u16* yh = blockIdx.y ? yhB : yhA;
    const int*   crow = cols + (size_t)srow * CAP;
    const float* vrow = vals + (size_t)srow * CAP;
    int cnt = nnz[srow];
    int nch = cnt >> 2;                 // even (cnt % 8 == 0), >= 4
    const u16* gpan = xh + panel * 512;
    float a[8] = {0.f,0.f,0.f,0.f,0.f,0.f,0.f,0.f};

    uint4 qA[CHUNK], qB[CHUNK];
    loadC4(qA, crow, 0,     gpan, lane);
    loadC4(qB, crow, CHUNK, gpan, lane);
    float vvA[CHUNK], vvB[CHUNK];
#pragma unroll
    for (int i = 0; i < CHUNK; ++i) {
      vvA[i] = vrow[i];
      vvB[i] = vrow[CHUNK + i];
    }

    int c2 = 0;
    for (; c2 + 2 < nch; c2 += 2) {
      float vvA2[CHUNK], vvB2[CHUNK];
#pragma unroll
      for (int i = 0; i < CHUNK; ++i) {
        vvA2[i] = vrow[(c2 + 2) * CHUNK + i];
        vvB2[i] = vrow[(c2 + 3) * CHUNK + i];
      }
      fmaC(qA, vvA, a);
      loadC4(qA, crow, (c2 + 2) * CHUNK, gpan, lane);
      fmaC(qB, vvB, a);
      loadC4(qB, crow, (c2 + 3) * CHUNK, gpan, lane);
#pragma unroll
      for (int i = 0; i < CHUNK; ++i) { vvA[i] = vvA2[i]; vvB[i] = vvB2[i]; }
    }
    fmaC(qA, vvA, a);
    fmaC(qB, vvB, a);

    size_t oh = (size_t)row * XHC + panel * 512 + lane * 8;
    uint4 o4;
    o4.x = pack2(a[0], a[1]); o4.y = pack2(a[2], a[3]);
    o4.z = pack2(a[4], a[5]); o4.w = pack2(a[6], a[7]);
    __builtin_nontemporal_store(o4.x, (unsigned*)(yh + oh));
    __builtin_nontemporal_store(o4.y, (unsigned*)(yh + oh) + 1);
    __builtin_nontemporal_store(o4.z, (unsigned*)(yh + oh) + 2);
    __builtin_nontemporal_store(o4.w, (unsigned*)(yh + oh) + 3);
  } else {
    int row = (bx - 8192) * 2 + wv;
    int srow = __builtin_amdgcn_readfirstlane(sup * NN + row);
    const u16* xs = blockIdx.y ? xiB : xiA;
    u16* yo = blockIdx.y ? yiB : yiA;
    const int*   crow = cols + (size_t)srow * CAP;
    const float* vrow = vals + (size_t)srow * CAP;
    int cnt = nnz[srow];
    float a = 0.f;
    for (int k0 = 0; k0 < cnt; k0 += 8) {
      int cc[8]; float vv[8];
#pragma unroll
      for (int i = 0; i < 8; ++i) { cc[i] = crow[k0 + i]; vv[i] = vrow[k0 + i]; }
      u16 q[8];
#pragma unroll
      for (int i = 0; i < 8; ++i) q[i] = xs[(size_t)cc[i] * XIC + lane];
#pragma unroll
      for (int i = 0; i < 8; ++i) a = fmaf(vv[i], bf1(q[i]), a);
    }
    yo[(size_t)row * XIC + lane] = f2bf(a);
  }
}

// ---------------- xi A-fragment, inlined ------------------------------------
// af element j (j=0..7) is k = quad*8+j of the 32-k xi scan:
//   k in [0,10): mat m=k>>1, half f=k&1, value xi_m[n][b*2+f]; k>=10: zero.
__device__ __forceinline__ short8 xi_frag(
    const u16* xi0, const u16* yi1, const u16* yi2, const u16* yi3,
    const u16* yi4, int n, int b, int quad) {
  unsigned a0 = 0, a1 = 0, a2 = 0, a3 = 0;
  size_t off = (size_t)n * 32 + b;
  if (quad == 0) {
    a0 = ((const unsigned*)xi0)[off];
    a1 = ((const unsigned*)yi1)[off];
    a2 = ((const unsigned*)yi2)[off];
    a3 = ((const unsigned*)yi3)[off];
  } else if (quad == 1) {
    a0 = ((const unsigned*)yi4)[off];
  }
  short8 af;
  ((unsigned*)&af)[0] = a0;
  ((unsigned*)&af)[1] = a1;
  ((unsigned*)&af)[2] = a2;
  ((unsigned*)&af)[3] = a3;
  return af;
}

// ---------------- gate: weight-stationary, 8 waves x 1 t, G n's per block ---
#define GATE_G 8
__global__ __launch_bounds__(512) void gate_mfma(
    const u16* __restrict__ xi0, const u16* __restrict__ yi1,
    const u16* __restrict__ yi2, const u16* __restrict__ yi3,
    const u16* __restrict__ yi4,
    const u16* __restrict__ h0, const u16* __restrict__ h1,
    const u16* __restrict__ h2, const u16* __restrict__ h3,
    const u16* __restrict__ h4,
    const u16* __restrict__ Wf, const float* __restrict__ bias,
    const float* __restrict__ hx,
    u16* __restrict__ xhp, float* __restrict__ ubuf) {
  int lane = threadIdx.x & 63;
  int t = threadIdx.x >> 6;            // 0..7: output tile (o = t*16+colo)
  int colo = lane & 15;
  int quad = lane >> 4;
  const u16* hm[5] = {h0, h1, h2, h3, h4};
  short8 bf[11];
#pragma unroll
  for (int ks = 0; ks < 11; ++ks)
    bf[ks] = *(const short8*)(Wf + (size_t)((t * 11 + ks) * 64 + lane) * 8);
  float bv = bias[t * 16 + colo];
  int o = t * 16 + colo;
  int n0 = blockIdx.x * GATE_G;
  for (int g = 0; g < GATE_G; ++g) {
    int n = n0 + g;
#pragma unroll
    for (int Mtile = 0; Mtile < 2; ++Mtile) {
      int aoff = (Mtile * 16 + colo) * 64 + quad * 8;
      short8 af[11];
#pragma unroll
      for (int ks = 0; ks < 10; ++ks)
        af[ks] = *(const short8*)(hm[ks >> 1] + (size_t)n * XHC + aoff + (ks & 1) * 32);
      af[10] = xi_frag(xi0, yi1, yi2, yi3, yi4, n, Mtile * 16 + colo, quad);
      float4v acc = (float4v){bv, bv, bv, bv};
#pragma unroll
      for (int ks = 0; ks < 11; ++ks)
        acc = __builtin_amdgcn_mfma_f32_16x16x32_bf16(af[ks], bf[ks], acc, 0, 0, 0);
      int brow0 = Mtile * 16 + quad * 4;
      if (t < 4) {                      // wave-uniform branch
#pragma unroll
        for (int r = 0; r < 4; ++r) {
          int b = brow0 + r;
          float s = sigmoidf_(acc[r]);
          float h = hx[(size_t)b * (NN * UU) + (size_t)n * UU + o];
          xhp[(size_t)n * XHC + b * 64 + o] = f2bf(s * h);
        }
      } else {
#pragma unroll
        for (int r = 0; r < 4; ++r) {
          int b = brow0 + r;
          float s = sigmoidf_(acc[r]);
          ubuf[(size_t)n * (BB * UU) + b * UU + (o - UU)] = s;
        }
      }
    }
  }
}

// ---------------- candidate: weight-stationary, 4 waves x 1 t ---------------
#define CAND_G 4
__global__ __launch_bounds__(256) void cand_mfma(
    const u16* __restrict__ xi0, const u16* __restrict__ yi1,
    const u16* __restrict__ yi2, const u16* __restrict__ yi3,
    const u16* __restrict__ yi4,
    const u16* __restrict__ h0, const u16* __restrict__ h1,
    const u16* __restrict__ h2, const u16* __restrict__ h3,
    const u16* __restrict__ h4,
    const u16* __restrict__ W2f, const float* __restrict__ b2,
    const float* __restrict__ hx, const float* __restrict__ ubuf,
    float* __restrict__ out) {
  int lane = threadIdx.x & 63;
  int t = threadIdx.x >> 6;            // 0..3
  int colo = lane & 15;
  int quad = lane >> 4;
  const u16* hm[5] = {h0, h1, h2, h3, h4};
  short8 bf[11];
#pragma unroll
  for (int ks = 0; ks < 11; ++ks)
    bf[ks] = *(const short8*)(W2f + (size_t)((t * 11 + ks) * 64 + lane) * 8);
  float bv = b2[t * 16 + colo];
  int o = t * 16 + colo;
  int n0 = blockIdx.x * CAND_G;
  for (int g = 0; g < CAND_G; ++g) {
    int n = n0 + g;
#pragma unroll
    for (int Mtile = 0; Mtile < 2; ++Mtile) {
      int aoff = (Mtile * 16 + colo) * 64 + quad * 8;
      short8 af[11];
#pragma unroll
      for (int ks = 0; ks < 10; ++ks)
        af[ks] = *(const short8*)(hm[ks >> 1] + (size_t)n * XHC + aoff + (ks & 1) * 32);
      af[10] = xi_frag(xi0, yi1, yi2, yi3, yi4, n, Mtile * 16 + colo, quad);
      float4v acc = (float4v){bv, bv, bv, bv};
#pragma unroll
      for (int ks = 0; ks < 11; ++ks)
        acc = __builtin_amdgcn_mfma_f32_16x16x32_bf16(af[ks], bf[ks], acc, 0, 0, 0);
      int brow0 = Mtile * 16 + quad * 4;
#pragma unroll
      for (int r = 0; r < 4; ++r) {
        int b = brow0 + r;
        float c = tanhf_(acc[r]);
        float u = ubuf[(size_t)n * (BB * UU) + b * UU + o];
        float h = hx[(size_t)b * (NN * UU) + (size_t)n * UU + o];
        out[(size_t)b * (NN * UU) + (size_t)n * UU + o] = u * h + (1.0f - u) * c;
      }
    }
  }
}

extern "C" void kernel_launch(void* const* d_in, const int* in_sizes, int n_in,
                              void* d_out, int out_size, void* d_ws, size_t ws_size,
                              hipStream_t stream) {
  const float* inp  = (const float*)d_in[0];
  const float* hx   = (const float*)d_in[1];
  const float* S0   = (const float*)d_in[2];
  const float* S1   = (const float*)d_in[3];
  const float* W    = (const float*)d_in[4];
  const float* bias = (const float*)d_in[5];
  const float* W2   = (const float*)d_in[6];
  const float* b2   = (const float*)d_in[7];
  float* out = (float*)d_out;

  char* ws = (char*)d_ws;
  const size_t XHB = (size_t)NN * XHC * sizeof(u16);
  const size_t XIB = (size_t)NN * XIC * sizeof(u16);
  u16* bufA  = (u16*)(ws);              // xh0
  u16* bufB  = (u16*)(ws + 1 * XHB);    // S@x
  u16* bufC  = (u16*)(ws + 2 * XHB);    // S@S@x
  u16* bufD  = (u16*)(ws + 3 * XHB);    // S1@x
  u16* bufE  = (u16*)(ws + 4 * XHB);    // S1@S1@x
  u16* bufA2 = (u16*)(ws + 5 * XHB);    // xh' (gate output; no in-place race)
  char* p = ws + 6 * XHB;
  u16* xi0 = (u16*)p;  p += XIB + 256;
  u16* yi1 = (u16*)p;  p += XIB + 256;
  u16* yi2 = (u16*)p;  p += XIB + 256;
  u16* yi3 = (u16*)p;  p += XIB + 256;
  u16* yi4 = (u16*)p;  p += XIB + 256;
  float* ubuf = (float*)p;             p += (size_t)NN * BB * UU * 4;
  int*   cols = (int*)p;               p += 2 * (size_t)NN * CAP * 4;
  float* vals = (float*)p;             p += 2 * (size_t)NN * CAP * 4;
  int*   nnzA = (int*)p;               p += 2 * (size_t)NN * 4;
  u16*   Wf   = (u16*)p;               p += (size_t)WF_G * 2;
  u16*   W2f  = (u16*)p;               p += (size_t)WF_C * 2;

  // fused prologue: prep_w | extract_csr | build_x0
  prologue<<<PW_BLK + 2048 + NN, 256, 0, stream>>>(
      W, W2, Wf, W2f, S0, S1, cols, vals, nnzA, inp, hx, xi0, bufA);

  // gconv1 hop1: both supports (shared source; xi tails)
  spmm_panel<<<dim3(10240, 2), 128, 0, stream>>>(cols, vals, nnzA,
      xi0, bufA, xi0, bufA, 0, yi1, bufB, yi3, bufD);
  // gconv1 hop2: both supports
  spmm_panel<<<dim3(10240, 2), 128, 0, stream>>>(cols, vals, nnzA,
      yi1, bufB, yi3, bufD, 0, yi2, bufC, yi4, bufE);

  // gate: reads gen-1 mats (bufA..E), writes xh' -> bufA2, u -> ubuf
  gate_mfma<<<NN / GATE_G, 512, 0, stream>>>(
      xi0, yi1, yi2, yi3, yi4,
      bufA, bufB, bufC, bufD, bufE,
      Wf, bias, hx, bufA2, ubuf);

  // gconv2 on xh' = bufA2 (xi mats unchanged; no xi tail)
  spmm_panel<<<dim3(8192, 2), 128, 0, stream>>>(cols, vals, nnzA,
      xi0, bufA2, xi0, bufA2, 0, yi1, bufB, yi3, bufD);
  spmm_panel<<<dim3(8192, 2), 128, 0, stream>>>(cols, vals, nnzA,
      yi1, bufB, yi3, bufD, 0, yi2, bufC, yi4, bufE);

  // candidate + final combine (gen-2 mats: m0 = bufA2)
  cand_mfma<<<NN / CAND_G, 256, 0, stream>>>(
      xi0, yi1, yi2, yi3, yi4,
      bufA2, bufB, bufC, bufD, bufE,
      W2f, b2, hx, ubuf, out);
}

// Round 9
// 552.734 us; speedup vs baseline: 1.0463x; 1.0463x over previous
//
#include <hip/hip_runtime.h>
#include <math.h>

// DCGRU cell, N=4096, B=32, U=64, F=66, M=5, 2 supports.
// R20: consolidation. gate/cand = exact R18 shape (256thr/4-wave, acc[4]/
// acc[2], LDS-staged writeback, in-place bufA) - the measured best; R17
// (128thr) and R19 (512thr weight-stationary) both regressed it: this
// workload is latency-hiding-bound, cache-served broadcast traffic is free,
// resident-wave parallelism is the currency. spmm = R12 local optimum
// (73.4us; R13/R15/R16 convergence-tested). KEEP R19's fused prologue
// (prep_w|extract_csr|build_x0, one dispatch, -2 launches - neutral-positive).

#define NN 4096
#define BB 32
#define UU 64
#define FF 66
#define MM 5
#define XHC 2048       // xh row elements (4096 B)
#define XIC 64         // xi row elements (128 B)
#define CAP 128        // max nnz/row, padded to %8 (min 16)
#define CHUNK 4
#define WF_G (8*11*64*8)
#define WF_C (4*11*64*8)
#define PW_BLK ((WF_G + WF_C + 255) / 256)   // 264

typedef unsigned short u16;
typedef __attribute__((ext_vector_type(8))) short short8;
typedef __attribute__((ext_vector_type(4))) float float4v;

__device__ __forceinline__ u16 f2bf(float f) {
  unsigned u = __float_as_uint(f);
  u += 0x7FFFu + ((u >> 16) & 1u);   // RNE
  return (u16)(u >> 16);
}
__device__ __forceinline__ unsigned pack2(float lo, float hi) {
  return (unsigned)f2bf(lo) | ((unsigned)f2bf(hi) << 16);
}
__device__ __forceinline__ float bflo(unsigned d) { return __uint_as_float(d << 16); }
__device__ __forceinline__ float bfhi(unsigned d) { return __uint_as_float(d & 0xFFFF0000u); }
__device__ __forceinline__ float bf1(u16 v) { return __uint_as_float((unsigned)v << 16); }

__device__ __forceinline__ float sigmoidf_(float x) {
  return 1.0f / (1.0f + __expf(-x));
}
__device__ __forceinline__ float tanhf_(float x) {
  x = fminf(fmaxf(x, -15.f), 15.f);
  float e = __expf(2.f * x);
  return (e - 1.f) / (e + 1.f);
}

// ---------------- weight fold helper ----------------------------------------
__device__ __forceinline__ float wfold(const float* W, int f, int m, int o, int O) {
  if (m == 0)
    return W[((size_t)f * MM + 0) * O + o] - W[((size_t)f * MM + 2) * O + o]
         - W[((size_t)f * MM + 4) * O + o];
  float v = W[((size_t)f * MM + m) * O + o];
  return (m == 2 || m == 4) ? 2.0f * v : v;
}

// ---------------- fused prologue: prep_w | extract_csr | build_x0 -----------
__global__ __launch_bounds__(256) void prologue(
    const float* __restrict__ W, const float* __restrict__ W2,
    u16* __restrict__ Wf, u16* __restrict__ W2f,
    const float* __restrict__ S0, const float* __restrict__ S1,
    int* __restrict__ cols, float* __restrict__ vals, int* __restrict__ nnz,
    const float* __restrict__ inp, const float* __restrict__ hx,
    u16* __restrict__ xi0, u16* __restrict__ xh0) {
  int bid = blockIdx.x;
  if (bid < PW_BLK) {
    // ---- prep_w: Chebyshev fold + k-scan fragment order ----
    int idx = bid * 256 + threadIdx.x;
    if (idx < WF_G) {
      int j = idx & 7, lane = (idx >> 3) & 63, q = idx >> 9;
      int ks = q % 11, t = q / 11;
      int o = t * 16 + (lane & 15);
      int qj = (lane >> 4) * 8 + j;
      float v = 0.f;
      if (ks < 10)      { v = wfold(W, 2 + (ks & 1) * 32 + qj, ks >> 1, o, 128); }
      else if (qj < 10) { v = wfold(W, qj & 1, qj >> 1, o, 128); }
      Wf[idx] = f2bf(v);
    } else if (idx < WF_G + WF_C) {
      int i2 = idx - WF_G;
      int j = i2 & 7, lane = (i2 >> 3) & 63, q = i2 >> 9;
      int ks = q % 11, t = q / 11;
      int o = t * 16 + (lane & 15);
      int qj = (lane >> 4) * 8 + j;
      float v = 0.f;
      if (ks < 10)      { v = wfold(W2, 2 + (ks & 1) * 32 + qj, ks >> 1, o, UU); }
      else if (qj < 10) { v = wfold(W2, qj & 1, qj >> 1, o, UU); }
      W2f[i2] = f2bf(v);
    }
  } else if (bid < PW_BLK + 2048) {
    // ---- extract_csr: rows zero-padded to %8, min 16 ----
    int e = bid - PW_BLK;
    int sup = e >> 10;
    int bx  = e & 1023;
    int wave = threadIdx.x >> 6;
    int lane = threadIdx.x & 63;
    int row  = bx * 4 + wave;
    const float* srow = (sup ? S1 : S0) + (size_t)row * NN;
    int*   crow = cols + ((size_t)sup * NN + row) * CAP;
    float* vrow = vals + ((size_t)sup * NN + row) * CAP;
    int base = 0;
    for (int j0 = 0; j0 < NN; j0 += 64) {
      float v = srow[j0 + lane];
      unsigned long long mask = __ballot(v != 0.0f);
      if (v != 0.0f) {
        int pos = base + __popcll(mask & ((1ull << lane) - 1ull));
        if (pos < CAP) { crow[pos] = j0 + lane; vrow[pos] = v; }
      }
      base += __popcll(mask);
    }
    if (base > CAP) base = CAP;
    int padded = (base + 7) & ~7;
    if (padded < 16) padded = 16;
    if (padded > CAP) padded = CAP;
    int p = base + lane;
    if (p < padded) { crow[p] = 0; vrow[p] = 0.0f; }
    if (lane == 0) nnz[sup * NN + row] = padded;
  } else {
    // ---- build_x0 ----
    int n = bid - PW_BLK - 2048;
    unsigned* xhd = (unsigned*)(xh0 + (size_t)n * XHC);
    for (int j = threadIdx.x; j < XHC / 2; j += 256) {
      int b = j >> 5, f2 = (j & 31) * 2;
      const float* h = hx + (size_t)b * (NN * UU) + (size_t)n * UU + f2;
      xhd[j] = pack2(h[0], h[1]);
    }
    if (threadIdx.x < 32) {
      int b = threadIdx.x;
      unsigned* xid = (unsigned*)(xi0 + (size_t)n * XIC);
      xid[b] = pack2(inp[(size_t)b * (NN * 2) + n * 2],
                     inp[(size_t)b * (NN * 2) + n * 2 + 1]);
    }
  }
}

// ---------------- SpMM: y = S@x. 4x1KB panels, VGPR gather, dbuf (R12) ------
__device__ __forceinline__ void fma8(float v, uint4 q, float* a) {
  a[0] = fmaf(v, bflo(q.x), a[0]); a[1] = fmaf(v, bfhi(q.x), a[1]);
  a[2] = fmaf(v, bflo(q.y), a[2]); a[3] = fmaf(v, bfhi(q.y), a[3]);
  a[4] = fmaf(v, bflo(q.z), a[4]); a[5] = fmaf(v, bfhi(q.z), a[5]);
  a[6] = fmaf(v, bflo(q.w), a[6]); a[7] = fmaf(v, bfhi(q.w), a[7]);
}

__device__ __forceinline__ void loadC4(uint4* q, const int* crow, int k0,
                                       const u16* gpan, int lane) {
#pragma unroll
  for (int i = 0; i < CHUNK; ++i) {
    int c = crow[k0 + i];                             // scalar (s_load)
    q[i] = *(const uint4*)(gpan + ((size_t)c << 11) + (lane << 3));
  }
}

__device__ __forceinline__ void fmaC(const uint4* q, const float* vv, float* a) {
#pragma unroll
  for (int i = 0; i < CHUNK; ++i) fma8(vv[i], q[i], a);
}

__global__ __launch_bounds__(128) void spmm_panel(
    const int* __restrict__ cols, const float* __restrict__ vals,
    const int* __restrict__ nnz,
    const u16* xiA, const u16* xhA, const u16* xiB, const u16* xhB,
    int sup_base,
    u16* yiA, u16* yhA, u16* yiB, u16* yhB) {
  int bx = blockIdx.x;
  int lane = threadIdx.x & 63;
  int wv = threadIdx.x >> 6;
  int sup = sup_base + blockIdx.y;

  if (bx < 8192) {
    int panel = bx & 3;
    int row = (bx >> 2) * 2 + wv;
    int srow = __builtin_amdgcn_readfirstlane(sup * NN + row);
    const u16* xh = blockIdx.y ? xhB : xhA;
    u16* yh = blockIdx.y ? yhB : yhA;
    const int*   crow = cols + (size_t)srow * CAP;
    const float* vrow = vals + (size_t)srow * CAP;
    int cnt = nnz[srow];
    int nch = cnt >> 2;                 // even (cnt % 8 == 0), >= 4
    const u16* gpan = xh + panel * 512;
    float a[8] = {0.f,0.f,0.f,0.f,0.f,0.f,0.f,0.f};

    uint4 qA[CHUNK], qB[CHUNK];
    loadC4(qA, crow, 0,     gpan, lane);
    loadC4(qB, crow, CHUNK, gpan, lane);
    float vvA[CHUNK], vvB[CHUNK];
#pragma unroll
    for (int i = 0; i < CHUNK; ++i) {
      vvA[i] = vrow[i];
      vvB[i] = vrow[CHUNK + i];
    }

    int c2 = 0;
    for (; c2 + 2 < nch; c2 += 2) {
      float vvA2[CHUNK], vvB2[CHUNK];
#pragma unroll
      for (int i = 0; i < CHUNK; ++i) {
        vvA2[i] = vrow[(c2 + 2) * CHUNK + i];
        vvB2[i] = vrow[(c2 + 3) * CHUNK + i];
      }
      fmaC(qA, vvA, a);
      loadC4(qA, crow, (c2 + 2) * CHUNK, gpan, lane);
      fmaC(qB, vvB, a);
      loadC4(qB, crow, (c2 + 3) * CHUNK, gpan, lane);
#pragma unroll
      for (int i = 0; i < CHUNK; ++i) { vvA[i] = vvA2[i]; vvB[i] = vvB2[i]; }
    }
    fmaC(qA, vvA, a);
    fmaC(qB, vvB, a);

    size_t oh = (size_t)row * XHC + panel * 512 + lane * 8;
    uint4 o4;
    o4.x = pack2(a[0], a[1]); o4.y = pack2(a[2], a[3]);
    o4.z = pack2(a[4], a[5]); o4.w = pack2(a[6], a[7]);
    __builtin_nontemporal_store(o4.x, (unsigned*)(yh + oh));
    __builtin_nontemporal_store(o4.y, (unsigned*)(yh + oh) + 1);
    __builtin_nontemporal_store(o4.z, (unsigned*)(yh + oh) + 2);
    __builtin_nontemporal_store(o4.w, (unsigned*)(yh + oh) + 3);
  } else {
    int row = (bx - 8192) * 2 + wv;
    int srow = __builtin_amdgcn_readfirstlane(sup * NN + row);
    const u16* xs = blockIdx.y ? xiB : xiA;
    u16* yo = blockIdx.y ? yiB : yiA;
    const int*   crow = cols + (size_t)srow * CAP;
    const float* vrow = vals + (size_t)srow * CAP;
    int cnt = nnz[srow];
    float a = 0.f;
    for (int k0 = 0; k0 < cnt; k0 += 8) {
      int cc[8]; float vv[8];
#pragma unroll
      for (int i = 0; i < 8; ++i) { cc[i] = crow[k0 + i]; vv[i] = vrow[k0 + i]; }
      u16 q[8];
#pragma unroll
      for (int i = 0; i < 8; ++i) q[i] = xs[(size_t)cc[i] * XIC + lane];
#pragma unroll
      for (int i = 0; i < 8; ++i) a = fmaf(vv[i], bf1(q[i]), a);
    }
    yo[(size_t)row * XIC + lane] = f2bf(a);
  }
}

// ---------------- xi A-fragment, inlined ------------------------------------
// af element j (j=0..7) is k = quad*8+j of the 32-k xi scan:
//   k in [0,10): mat m=k>>1, half f=k&1, value xi_m[n][b*2+f]; k>=10: zero.
__device__ __forceinline__ short8 xi_frag(
    const u16* xi0, const u16* yi1, const u16* yi2, const u16* yi3,
    const u16* yi4, int n, int b, int quad) {
  unsigned a0 = 0, a1 = 0, a2 = 0, a3 = 0;
  size_t off = (size_t)n * 32 + b;
  if (quad == 0) {
    a0 = ((const unsigned*)xi0)[off];
    a1 = ((const unsigned*)yi1)[off];
    a2 = ((const unsigned*)yi2)[off];
    a3 = ((const unsigned*)yi3)[off];
  } else if (quad == 1) {
    a0 = ((const unsigned*)yi4)[off];
  }
  short8 af;
  ((unsigned*)&af)[0] = a0;
  ((unsigned*)&af)[1] = a1;
  ((unsigned*)&af)[2] = a2;
  ((unsigned*)&af)[3] = a3;
  return af;
}

// ---------------- gate: 256 thr, wave = (Mtile, 4 N-tiles) (R18) ------------
__global__ __launch_bounds__(256) void gate_mfma(
    const u16* __restrict__ xi0, const u16* __restrict__ yi1,
    const u16* __restrict__ yi2, const u16* __restrict__ yi3,
    const u16* __restrict__ yi4,
    const u16* h0, const u16* __restrict__ h1, const u16* __restrict__ h2,
    const u16* __restrict__ h3, const u16* __restrict__ h4,
    const u16* __restrict__ Wf, const float* __restrict__ bias,
    const float* __restrict__ hx,
    u16* xhp, float* __restrict__ ubuf) {
  __shared__ u16 lt[BB * UU];           // r*hx staging for coalesced writeback
  int n = blockIdx.x;
  int lane = threadIdx.x & 63;
  int w = threadIdx.x >> 6;
  int Mtile = w & 1;
  int Nbase = (w >> 1) * 4;
  int colo = lane & 15;
  int quad = lane >> 4;
  const u16* hm[5] = {h0, h1, h2, h3, h4};
  float4v acc[4];
#pragma unroll
  for (int t = 0; t < 4; ++t) {
    float bv = bias[(Nbase + t) * 16 + colo];
    acc[t] = (float4v){bv, bv, bv, bv};
  }
  int aoff = (Mtile * 16 + colo) * 64 + quad * 8;  // within an xh row
#pragma unroll
  for (int ks = 0; ks < 10; ++ks) {
    short8 af = *(const short8*)(hm[ks >> 1] + (size_t)n * XHC + aoff + (ks & 1) * 32);
#pragma unroll
    for (int t = 0; t < 4; ++t) {
      short8 bf = *(const short8*)(Wf + (size_t)(((Nbase + t) * 11 + ks) * 64 + lane) * 8);
      acc[t] = __builtin_amdgcn_mfma_f32_16x16x32_bf16(af, bf, acc[t], 0, 0, 0);
    }
  }
  {
    short8 af = xi_frag(xi0, yi1, yi2, yi3, yi4, n, Mtile * 16 + colo, quad);
#pragma unroll
    for (int t = 0; t < 4; ++t) {
      short8 bf = *(const short8*)(Wf + (size_t)(((Nbase + t) * 11 + 10) * 64 + lane) * 8);
      acc[t] = __builtin_amdgcn_mfma_f32_16x16x32_bf16(af, bf, acc[t], 0, 0, 0);
    }
  }
  int brow0 = Mtile * 16 + quad * 4;
#pragma unroll
  for (int t = 0; t < 4; ++t) {
    int o = (Nbase + t) * 16 + colo;
#pragma unroll
    for (int r = 0; r < 4; ++r) {
      int b = brow0 + r;
      float s = sigmoidf_(acc[t][r]);
      if (o < UU) {
        float h = hx[(size_t)b * (NN * UU) + (size_t)n * UU + o];
        lt[b * UU + o] = f2bf(s * h);
      } else {
        ubuf[(size_t)n * (BB * UU) + b * UU + (o - UU)] = s;
      }
    }
  }
  __syncthreads();
  unsigned* xrow = (unsigned*)(xhp + (size_t)n * XHC);
  const unsigned* ltd = (const unsigned*)lt;
  for (int j = threadIdx.x; j < XHC / 2; j += 256)
    xrow[j] = ltd[j];
}

// ---------------- candidate: 256 thr, wave = (Mtile, 2 N-tiles) (R18) -------
__global__ __launch_bounds__(256) void cand_mfma(
    const u16* __restrict__ xi0, const u16* __restrict__ yi1,
    const u16* __restrict__ yi2, const u16* __restrict__ yi3,
    const u16* __restrict__ yi4,
    const u16* __restrict__ h0, const u16* __restrict__ h1,
    const u16* __restrict__ h2, const u16* __restrict__ h3,
    const u16* __restrict__ h4,
    const u16* __restrict__ W2f, const float* __restrict__ b2,
    const float* __restrict__ hx, const float* __restrict__ ubuf,
    float* __restrict__ out) {
  int n = blockIdx.x;
  int lane = threadIdx.x & 63;
  int w = threadIdx.x >> 6;
  int Mtile = w & 1;
  int Nbase = (w >> 1) * 2;
  int colo = lane & 15;
  int quad = lane >> 4;
  const u16* hm[5] = {h0, h1, h2, h3, h4};
  float4v acc[2];
#pragma unroll
  for (int t = 0; t < 2; ++t) {
    float bv = b2[(Nbase + t) * 16 + colo];
    acc[t] = (float4v){bv, bv, bv, bv};
  }
  int aoff = (Mtile * 16 + colo) * 64 + quad * 8;
#pragma unroll
  for (int ks = 0; ks < 10; ++ks) {
    short8 af = *(const short8*)(hm[ks >> 1] + (size_t)n * XHC + aoff + (ks & 1) * 32);
#pragma unroll
    for (int t = 0; t < 2; ++t) {
      short8 bf = *(const short8*)(W2f + (size_t)(((Nbase + t) * 11 + ks) * 64 + lane) * 8);
      acc[t] = __builtin_amdgcn_mfma_f32_16x16x32_bf16(af, bf, acc[t], 0, 0, 0);
    }
  }
  {
    short8 af = xi_frag(xi0, yi1, yi2, yi3, yi4, n, Mtile * 16 + colo, quad);
#pragma unroll
    for (int t = 0; t < 2; ++t) {
      short8 bf = *(const short8*)(W2f + (size_t)(((Nbase + t) * 11 + 10) * 64 + lane) * 8);
      acc[t] = __builtin_amdgcn_mfma_f32_16x16x32_bf16(af, bf, acc[t], 0, 0, 0);
    }
  }
  int brow0 = Mtile * 16 + quad * 4;
#pragma unroll
  for (int t = 0; t < 2; ++t) {
    int o = (Nbase + t) * 16 + colo;
#pragma unroll
    for (int r = 0; r < 4; ++r) {
      int b = brow0 + r;
      float c = tanhf_(acc[t][r]);
      float u = ubuf[(size_t)n * (BB * UU) + b * UU + o];
      float h = hx[(size_t)b * (NN * UU) + (size_t)n * UU + o];
      out[(size_t)b * (NN * UU) + (size_t)n * UU + o] = u * h + (1.0f - u) * c;
    }
  }
}

extern "C" void kernel_launch(void* const* d_in, const int* in_sizes, int n_in,
                              void* d_out, int out_size, void* d_ws, size_t ws_size,
                              hipStream_t stream) {
  const float* inp  = (const float*)d_in[0];
  const float* hx   = (const float*)d_in[1];
  const float* S0   = (const float*)d_in[2];
  const float* S1   = (const float*)d_in[3];
  const float* W    = (const float*)d_in[4];
  const float* bias = (const float*)d_in[5];
  const float* W2   = (const float*)d_in[6];
  const float* b2   = (const float*)d_in[7];
  float* out = (float*)d_out;

  char* ws = (char*)d_ws;
  const size_t XHB = (size_t)NN * XHC * sizeof(u16);
  const size_t XIB = (size_t)NN * XIC * sizeof(u16);
  u16* bufA = (u16*)(ws);              // xh0 -> xh'
  u16* bufB = (u16*)(ws + 1 * XHB);    // S0@x
  u16* bufC = (u16*)(ws + 2 * XHB);    // S0@S0@x
  u16* bufD = (u16*)(ws + 3 * XHB);    // S1@x
  u16* bufE = (u16*)(ws + 4 * XHB);    // S1@S1@x
  char* p = ws + 5 * XHB;
  u16* xi0 = (u16*)p;  p += XIB + 256;
  u16* yi1 = (u16*)p;  p += XIB + 256;
  u16* yi2 = (u16*)p;  p += XIB + 256;
  u16* yi3 = (u16*)p;  p += XIB + 256;
  u16* yi4 = (u16*)p;  p += XIB + 256;
  float* ubuf = (float*)p;             p += (size_t)NN * BB * UU * 4;
  int*   cols = (int*)p;               p += 2 * (size_t)NN * CAP * 4;
  float* vals = (float*)p;             p += 2 * (size_t)NN * CAP * 4;
  int*   nnzA = (int*)p;               p += 2 * (size_t)NN * 4;
  u16*   Wf   = (u16*)p;               p += (size_t)WF_G * 2;
  u16*   W2f  = (u16*)p;               p += (size_t)WF_C * 2;

  // fused prologue: prep_w | extract_csr | build_x0
  prologue<<<PW_BLK + 2048 + NN, 256, 0, stream>>>(
      W, W2, Wf, W2f, S0, S1, cols, vals, nnzA, inp, hx, xi0, bufA);

  // gconv1 hop1: both supports (shared source; xi tails)
  spmm_panel<<<dim3(10240, 2), 128, 0, stream>>>(cols, vals, nnzA,
      xi0, bufA, xi0, bufA, 0, yi1, bufB, yi3, bufD);
  // gconv1 hop2: both supports
  spmm_panel<<<dim3(10240, 2), 128, 0, stream>>>(cols, vals, nnzA,
      yi1, bufB, yi3, bufD, 0, yi2, bufC, yi4, bufE);

  // gate: writes xh' in place into bufA, u -> ubuf (xi frags read inline)
  gate_mfma<<<NN, 256, 0, stream>>>(xi0, yi1, yi2, yi3, yi4,
                                    bufA, bufB, bufC, bufD, bufE,
                                    Wf, bias, hx, bufA, ubuf);

  // gconv2 on xh' (xi mats unchanged; no xi tail)
  spmm_panel<<<dim3(8192, 2), 128, 0, stream>>>(cols, vals, nnzA,
      xi0, bufA, xi0, bufA, 0, yi1, bufB, yi3, bufD);
  spmm_panel<<<dim3(8192, 2), 128, 0, stream>>>(cols, vals, nnzA,
      yi1, bufB, yi3, bufD, 0, yi2, bufC, yi4, bufE);

  // candidate + final combine
  cand_mfma<<<NN, 256, 0, stream>>>(xi0, yi1, yi2, yi3, yi4,
                                    bufA, bufB, bufC, bufD, bufE,
                                    W2f, b2, hx, ubuf, out);
}

// Round 10
// 547.418 us; speedup vs baseline: 1.0565x; 1.0097x over previous
//
#include <hip/hip_runtime.h>
#include <math.h>

// DCGRU cell, N=4096, B=32, U=64, F=66, M=5, 2 supports.
// R21: R20 + vectorized prologue. extract_csr reads S as float4/lane (16B,
// 1KB/wave/iter, 64->16 iters) with order-PRESERVING compaction: 4 ballots
// per chunk, lane base = base + sum popcll(m_e & below), intra-lane offset
// = count of earlier nonzero elems in own float4 -> position key (lane,e)
// == original column order 4l+e, so nnz order (and absmax) is bit-identical.
// build_x0 reads hx as float4/lane. R20 measured prologue 74.9us vs ~25us
// BW floor (161MB compulsory) - scalar loads + 64-deep ballot chain were
// the gap. spmm/gate/cand untouched (measured-best R12/R18 shapes).

#define NN 4096
#define BB 32
#define UU 64
#define FF 66
#define MM 5
#define XHC 2048       // xh row elements (4096 B)
#define XIC 64         // xi row elements (128 B)
#define CAP 128        // max nnz/row, padded to %8 (min 16)
#define CHUNK 4
#define WF_G (8*11*64*8)
#define WF_C (4*11*64*8)
#define PW_BLK ((WF_G + WF_C + 255) / 256)   // 264

typedef unsigned short u16;
typedef __attribute__((ext_vector_type(8))) short short8;
typedef __attribute__((ext_vector_type(4))) float float4v;

__device__ __forceinline__ u16 f2bf(float f) {
  unsigned u = __float_as_uint(f);
  u += 0x7FFFu + ((u >> 16) & 1u);   // RNE
  return (u16)(u >> 16);
}
__device__ __forceinline__ unsigned pack2(float lo, float hi) {
  return (unsigned)f2bf(lo) | ((unsigned)f2bf(hi) << 16);
}
__device__ __forceinline__ float bflo(unsigned d) { return __uint_as_float(d << 16); }
__device__ __forceinline__ float bfhi(unsigned d) { return __uint_as_float(d & 0xFFFF0000u); }
__device__ __forceinline__ float bf1(u16 v) { return __uint_as_float((unsigned)v << 16); }

__device__ __forceinline__ float sigmoidf_(float x) {
  return 1.0f / (1.0f + __expf(-x));
}
__device__ __forceinline__ float tanhf_(float x) {
  x = fminf(fmaxf(x, -15.f), 15.f);
  float e = __expf(2.f * x);
  return (e - 1.f) / (e + 1.f);
}

// ---------------- weight fold helper ----------------------------------------
__device__ __forceinline__ float wfold(const float* W, int f, int m, int o, int O) {
  if (m == 0)
    return W[((size_t)f * MM + 0) * O + o] - W[((size_t)f * MM + 2) * O + o]
         - W[((size_t)f * MM + 4) * O + o];
  float v = W[((size_t)f * MM + m) * O + o];
  return (m == 2 || m == 4) ? 2.0f * v : v;
}

// ---------------- fused prologue: prep_w | extract_csr | build_x0 -----------
__global__ __launch_bounds__(256) void prologue(
    const float* __restrict__ W, const float* __restrict__ W2,
    u16* __restrict__ Wf, u16* __restrict__ W2f,
    const float* __restrict__ S0, const float* __restrict__ S1,
    int* __restrict__ cols, float* __restrict__ vals, int* __restrict__ nnz,
    const float* __restrict__ inp, const float* __restrict__ hx,
    u16* __restrict__ xi0, u16* __restrict__ xh0) {
  int bid = blockIdx.x;
  if (bid < PW_BLK) {
    // ---- prep_w: Chebyshev fold + k-scan fragment order ----
    int idx = bid * 256 + threadIdx.x;
    if (idx < WF_G) {
      int j = idx & 7, lane = (idx >> 3) & 63, q = idx >> 9;
      int ks = q % 11, t = q / 11;
      int o = t * 16 + (lane & 15);
      int qj = (lane >> 4) * 8 + j;
      float v = 0.f;
      if (ks < 10)      { v = wfold(W, 2 + (ks & 1) * 32 + qj, ks >> 1, o, 128); }
      else if (qj < 10) { v = wfold(W, qj & 1, qj >> 1, o, 128); }
      Wf[idx] = f2bf(v);
    } else if (idx < WF_G + WF_C) {
      int i2 = idx - WF_G;
      int j = i2 & 7, lane = (i2 >> 3) & 63, q = i2 >> 9;
      int ks = q % 11, t = q / 11;
      int o = t * 16 + (lane & 15);
      int qj = (lane >> 4) * 8 + j;
      float v = 0.f;
      if (ks < 10)      { v = wfold(W2, 2 + (ks & 1) * 32 + qj, ks >> 1, o, UU); }
      else if (qj < 10) { v = wfold(W2, qj & 1, qj >> 1, o, UU); }
      W2f[i2] = f2bf(v);
    }
  } else if (bid < PW_BLK + 2048) {
    // ---- extract_csr: float4 scan, order-preserving compaction ----
    int e = bid - PW_BLK;
    int sup = e >> 10;
    int bx  = e & 1023;
    int wave = threadIdx.x >> 6;
    int lane = threadIdx.x & 63;
    int row  = bx * 4 + wave;
    const float4* srow4 = (const float4*)((sup ? S1 : S0) + (size_t)row * NN);
    int*   crow = cols + ((size_t)sup * NN + row) * CAP;
    float* vrow = vals + ((size_t)sup * NN + row) * CAP;
    unsigned long long below = (1ull << lane) - 1ull;
    int base = 0;
    for (int it = 0; it < NN / 256; ++it) {        // 16 chunks of 256 cols
      float4 v = srow4[it * 64 + lane];
      unsigned long long m0 = __ballot(v.x != 0.0f);
      unsigned long long m1 = __ballot(v.y != 0.0f);
      unsigned long long m2 = __ballot(v.z != 0.0f);
      unsigned long long m3 = __ballot(v.w != 0.0f);
      int pos = base + __popcll(m0 & below) + __popcll(m1 & below)
                     + __popcll(m2 & below) + __popcll(m3 & below);
      int c0 = it * 256 + lane * 4;
      if (v.x != 0.0f) { if (pos < CAP) { crow[pos] = c0;     vrow[pos] = v.x; } ++pos; }
      if (v.y != 0.0f) { if (pos < CAP) { crow[pos] = c0 + 1; vrow[pos] = v.y; } ++pos; }
      if (v.z != 0.0f) { if (pos < CAP) { crow[pos] = c0 + 2; vrow[pos] = v.z; } ++pos; }
      if (v.w != 0.0f) { if (pos < CAP) { crow[pos] = c0 + 3; vrow[pos] = v.w; } ++pos; }
      base += __popcll(m0) + __popcll(m1) + __popcll(m2) + __popcll(m3);
    }
    if (base > CAP) base = CAP;
    int padded = (base + 7) & ~7;
    if (padded < 16) padded = 16;
    if (padded > CAP) padded = CAP;
    int p = base + lane;
    if (p < padded) { crow[p] = 0; vrow[p] = 0.0f; }
    if (lane == 0) nnz[sup * NN + row] = padded;
  } else {
    // ---- build_x0: float4 hx reads ----
    int n = bid - PW_BLK - 2048;
    unsigned* xhd = (unsigned*)(xh0 + (size_t)n * XHC);
    for (int j = threadIdx.x; j < XHC / 4; j += 256) {   // 512 jobs x 4 floats
      int b = j >> 4, f4 = (j & 15) * 4;
      float4 h = *(const float4*)(hx + (size_t)b * (NN * UU) + (size_t)n * UU + f4);
      xhd[j * 2]     = pack2(h.x, h.y);
      xhd[j * 2 + 1] = pack2(h.z, h.w);
    }
    if (threadIdx.x < 32) {
      int b = threadIdx.x;
      unsigned* xid = (unsigned*)(xi0 + (size_t)n * XIC);
      xid[b] = pack2(inp[(size_t)b * (NN * 2) + n * 2],
                     inp[(size_t)b * (NN * 2) + n * 2 + 1]);
    }
  }
}

// ---------------- SpMM: y = S@x. 4x1KB panels, VGPR gather, dbuf (R12) ------
__device__ __forceinline__ void fma8(float v, uint4 q, float* a) {
  a[0] = fmaf(v, bflo(q.x), a[0]); a[1] = fmaf(v, bfhi(q.x), a[1]);
  a[2] = fmaf(v, bflo(q.y), a[2]); a[3] = fmaf(v, bfhi(q.y), a[3]);
  a[4] = fmaf(v, bflo(q.z), a[4]); a[5] = fmaf(v, bfhi(q.z), a[5]);
  a[6] = fmaf(v, bflo(q.w), a[6]); a[7] = fmaf(v, bfhi(q.w), a[7]);
}

__device__ __forceinline__ void loadC4(uint4* q, const int* crow, int k0,
                                       const u16* gpan, int lane) {
#pragma unroll
  for (int i = 0; i < CHUNK; ++i) {
    int c = crow[k0 + i];                             // scalar (s_load)
    q[i] = *(const uint4*)(gpan + ((size_t)c << 11) + (lane << 3));
  }
}

__device__ __forceinline__ void fmaC(const uint4* q, const float* vv, float* a) {
#pragma unroll
  for (int i = 0; i < CHUNK; ++i) fma8(vv[i], q[i], a);
}

__global__ __launch_bounds__(128) void spmm_panel(
    const int* __restrict__ cols, const float* __restrict__ vals,
    const int* __restrict__ nnz,
    const u16* xiA, const u16* xhA, const u16* xiB, const u16* xhB,
    int sup_base,
    u16* yiA, u16* yhA, u16* yiB, u16* yhB) {
  int bx = blockIdx.x;
  int lane = threadIdx.x & 63;
  int wv = threadIdx.x >> 6;
  int sup = sup_base + blockIdx.y;

  if (bx < 8192) {
    int panel = bx & 3;
    int row = (bx >> 2) * 2 + wv;
    int srow = __builtin_amdgcn_readfirstlane(sup * NN + row);
    const u16* xh = blockIdx.y ? xhB : xhA;
    u16* yh = blockIdx.y ? yhB : yhA;
    const int*   crow = cols + (size_t)srow * CAP;
    const float* vrow = vals + (size_t)srow * CAP;
    int cnt = nnz[srow];
    int nch = cnt >> 2;                 // even (cnt % 8 == 0), >= 4
    const u16* gpan = xh + panel * 512;
    float a[8] = {0.f,0.f,0.f,0.f,0.f,0.f,0.f,0.f};

    uint4 qA[CHUNK], qB[CHUNK];
    loadC4(qA, crow, 0,     gpan, lane);
    loadC4(qB, crow, CHUNK, gpan, lane);
    float vvA[CHUNK], vvB[CHUNK];
#pragma unroll
    for (int i = 0; i < CHUNK; ++i) {
      vvA[i] = vrow[i];
      vvB[i] = vrow[CHUNK + i];
    }

    int c2 = 0;
    for (; c2 + 2 < nch; c2 += 2) {
      float vvA2[CHUNK], vvB2[CHUNK];
#pragma unroll
      for (int i = 0; i < CHUNK; ++i) {
        vvA2[i] = vrow[(c2 + 2) * CHUNK + i];
        vvB2[i] = vrow[(c2 + 3) * CHUNK + i];
      }
      fmaC(qA, vvA, a);
      loadC4(qA, crow, (c2 + 2) * CHUNK, gpan, lane);
      fmaC(qB, vvB, a);
      loadC4(qB, crow, (c2 + 3) * CHUNK, gpan, lane);
#pragma unroll
      for (int i = 0; i < CHUNK; ++i) { vvA[i] = vvA2[i]; vvB[i] = vvB2[i]; }
    }
    fmaC(qA, vvA, a);
    fmaC(qB, vvB, a);

    size_t oh = (size_t)row * XHC + panel * 512 + lane * 8;
    uint4 o4;
    o4.x = pack2(a[0], a[1]); o4.y = pack2(a[2], a[3]);
    o4.z = pack2(a[4], a[5]); o4.w = pack2(a[6], a[7]);
    __builtin_nontemporal_store(o4.x, (unsigned*)(yh + oh));
    __builtin_nontemporal_store(o4.y, (unsigned*)(yh + oh) + 1);
    __builtin_nontemporal_store(o4.z, (unsigned*)(yh + oh) + 2);
    __builtin_nontemporal_store(o4.w, (unsigned*)(yh + oh) + 3);
  } else {
    int row = (bx - 8192) * 2 + wv;
    int srow = __builtin_amdgcn_readfirstlane(sup * NN + row);
    const u16* xs = blockIdx.y ? xiB : xiA;
    u16* yo = blockIdx.y ? yiB : yiA;
    const int*   crow = cols + (size_t)srow * CAP;
    const float* vrow = vals + (size_t)srow * CAP;
    int cnt = nnz[srow];
    float a = 0.f;
    for (int k0 = 0; k0 < cnt; k0 += 8) {
      int cc[8]; float vv[8];
#pragma unroll
      for (int i = 0; i < 8; ++i) { cc[i] = crow[k0 + i]; vv[i] = vrow[k0 + i]; }
      u16 q[8];
#pragma unroll
      for (int i = 0; i < 8; ++i) q[i] = xs[(size_t)cc[i] * XIC + lane];
#pragma unroll
      for (int i = 0; i < 8; ++i) a = fmaf(vv[i], bf1(q[i]), a);
    }
    yo[(size_t)row * XIC + lane] = f2bf(a);
  }
}

// ---------------- xi A-fragment, inlined ------------------------------------
// af element j (j=0..7) is k = quad*8+j of the 32-k xi scan:
//   k in [0,10): mat m=k>>1, half f=k&1, value xi_m[n][b*2+f]; k>=10: zero.
__device__ __forceinline__ short8 xi_frag(
    const u16* xi0, const u16* yi1, const u16* yi2, const u16* yi3,
    const u16* yi4, int n, int b, int quad) {
  unsigned a0 = 0, a1 = 0, a2 = 0, a3 = 0;
  size_t off = (size_t)n * 32 + b;
  if (quad == 0) {
    a0 = ((const unsigned*)xi0)[off];
    a1 = ((const unsigned*)yi1)[off];
    a2 = ((const unsigned*)yi2)[off];
    a3 = ((const unsigned*)yi3)[off];
  } else if (quad == 1) {
    a0 = ((const unsigned*)yi4)[off];
  }
  short8 af;
  ((unsigned*)&af)[0] = a0;
  ((unsigned*)&af)[1] = a1;
  ((unsigned*)&af)[2] = a2;
  ((unsigned*)&af)[3] = a3;
  return af;
}

// ---------------- gate: 256 thr, wave = (Mtile, 4 N-tiles) (R18) ------------
__global__ __launch_bounds__(256) void gate_mfma(
    const u16* __restrict__ xi0, const u16* __restrict__ yi1,
    const u16* __restrict__ yi2, const u16* __restrict__ yi3,
    const u16* __restrict__ yi4,
    const u16* h0, const u16* __restrict__ h1, const u16* __restrict__ h2,
    const u16* __restrict__ h3, const u16* __restrict__ h4,
    const u16* __restrict__ Wf, const float* __restrict__ bias,
    const float* __restrict__ hx,
    u16* xhp, float* __restrict__ ubuf) {
  __shared__ u16 lt[BB * UU];           // r*hx staging for coalesced writeback
  int n = blockIdx.x;
  int lane = threadIdx.x & 63;
  int w = threadIdx.x >> 6;
  int Mtile = w & 1;
  int Nbase = (w >> 1) * 4;
  int colo = lane & 15;
  int quad = lane >> 4;
  const u16* hm[5] = {h0, h1, h2, h3, h4};
  float4v acc[4];
#pragma unroll
  for (int t = 0; t < 4; ++t) {
    float bv = bias[(Nbase + t) * 16 + colo];
    acc[t] = (float4v){bv, bv, bv, bv};
  }
  int aoff = (Mtile * 16 + colo) * 64 + quad * 8;  // within an xh row
#pragma unroll
  for (int ks = 0; ks < 10; ++ks) {
    short8 af = *(const short8*)(hm[ks >> 1] + (size_t)n * XHC + aoff + (ks & 1) * 32);
#pragma unroll
    for (int t = 0; t < 4; ++t) {
      short8 bf = *(const short8*)(Wf + (size_t)(((Nbase + t) * 11 + ks) * 64 + lane) * 8);
      acc[t] = __builtin_amdgcn_mfma_f32_16x16x32_bf16(af, bf, acc[t], 0, 0, 0);
    }
  }
  {
    short8 af = xi_frag(xi0, yi1, yi2, yi3, yi4, n, Mtile * 16 + colo, quad);
#pragma unroll
    for (int t = 0; t < 4; ++t) {
      short8 bf = *(const short8*)(Wf + (size_t)(((Nbase + t) * 11 + 10) * 64 + lane) * 8);
      acc[t] = __builtin_amdgcn_mfma_f32_16x16x32_bf16(af, bf, acc[t], 0, 0, 0);
    }
  }
  int brow0 = Mtile * 16 + quad * 4;
#pragma unroll
  for (int t = 0; t < 4; ++t) {
    int o = (Nbase + t) * 16 + colo;
#pragma unroll
    for (int r = 0; r < 4; ++r) {
      int b = brow0 + r;
      float s = sigmoidf_(acc[t][r]);
      if (o < UU) {
        float h = hx[(size_t)b * (NN * UU) + (size_t)n * UU + o];
        lt[b * UU + o] = f2bf(s * h);
      } else {
        ubuf[(size_t)n * (BB * UU) + b * UU + (o - UU)] = s;
      }
    }
  }
  __syncthreads();
  unsigned* xrow = (unsigned*)(xhp + (size_t)n * XHC);
  const unsigned* ltd = (const unsigned*)lt;
  for (int j = threadIdx.x; j < XHC / 2; j += 256)
    xrow[j] = ltd[j];
}

// ---------------- candidate: 256 thr, wave = (Mtile, 2 N-tiles) (R18) -------
__global__ __launch_bounds__(256) void cand_mfma(
    const u16* __restrict__ xi0, const u16* __restrict__ yi1,
    const u16* __restrict__ yi2, const u16* __restrict__ yi3,
    const u16* __restrict__ yi4,
    const u16* __restrict__ h0, const u16* __restrict__ h1,
    const u16* __restrict__ h2, const u16* __restrict__ h3,
    const u16* __restrict__ h4,
    const u16* __restrict__ W2f, const float* __restrict__ b2,
    const float* __restrict__ hx, const float* __restrict__ ubuf,
    float* __restrict__ out) {
  int n = blockIdx.x;
  int lane = threadIdx.x & 63;
  int w = threadIdx.x >> 6;
  int Mtile = w & 1;
  int Nbase = (w >> 1) * 2;
  int colo = lane & 15;
  int quad = lane >> 4;
  const u16* hm[5] = {h0, h1, h2, h3, h4};
  float4v acc[2];
#pragma unroll
  for (int t = 0; t < 2; ++t) {
    float bv = b2[(Nbase + t) * 16 + colo];
    acc[t] = (float4v){bv, bv, bv, bv};
  }
  int aoff = (Mtile * 16 + colo) * 64 + quad * 8;
#pragma unroll
  for (int ks = 0; ks < 10; ++ks) {
    short8 af = *(const short8*)(hm[ks >> 1] + (size_t)n * XHC + aoff + (ks & 1) * 32);
#pragma unroll
    for (int t = 0; t < 2; ++t) {
      short8 bf = *(const short8*)(W2f + (size_t)(((Nbase + t) * 11 + ks) * 64 + lane) * 8);
      acc[t] = __builtin_amdgcn_mfma_f32_16x16x32_bf16(af, bf, acc[t], 0, 0, 0);
    }
  }
  {
    short8 af = xi_frag(xi0, yi1, yi2, yi3, yi4, n, Mtile * 16 + colo, quad);
#pragma unroll
    for (int t = 0; t < 2; ++t) {
      short8 bf = *(const short8*)(W2f + (size_t)(((Nbase + t) * 11 + 10) * 64 + lane) * 8);
      acc[t] = __builtin_amdgcn_mfma_f32_16x16x32_bf16(af, bf, acc[t], 0, 0, 0);
    }
  }
  int brow0 = Mtile * 16 + quad * 4;
#pragma unroll
  for (int t = 0; t < 2; ++t) {
    int o = (Nbase + t) * 16 + colo;
#pragma unroll
    for (int r = 0; r < 4; ++r) {
      int b = brow0 + r;
      float c = tanhf_(acc[t][r]);
      float u = ubuf[(size_t)n * (BB * UU) + b * UU + o];
      float h = hx[(size_t)b * (NN * UU) + (size_t)n * UU + o];
      out[(size_t)b * (NN * UU) + (size_t)n * UU + o] = u * h + (1.0f - u) * c;
    }
  }
}

extern "C" void kernel_launch(void* const* d_in, const int* in_sizes, int n_in,
                              void* d_out, int out_size, void* d_ws, size_t ws_size,
                              hipStream_t stream) {
  const float* inp  = (const float*)d_in[0];
  const float* hx   = (const float*)d_in[1];
  const float* S0   = (const float*)d_in[2];
  const float* S1   = (const float*)d_in[3];
  const float* W    = (const float*)d_in[4];
  const float* bias = (const float*)d_in[5];
  const float* W2   = (const float*)d_in[6];
  const float* b2   = (const float*)d_in[7];
  float* out = (float*)d_out;

  char* ws = (char*)d_ws;
  const size_t XHB = (size_t)NN * XHC * sizeof(u16);
  const size_t XIB = (size_t)NN * XIC * sizeof(u16);
  u16* bufA = (u16*)(ws);              // xh0 -> xh'
  u16* bufB = (u16*)(ws + 1 * XHB);    // S0@x
  u16* bufC = (u16*)(ws + 2 * XHB);    // S0@S0@x
  u16* bufD = (u16*)(ws + 3 * XHB);    // S1@x
  u16* bufE = (u16*)(ws + 4 * XHB);    // S1@S1@x
  char* p = ws + 5 * XHB;
  u16* xi0 = (u16*)p;  p += XIB + 256;
  u16* yi1 = (u16*)p;  p += XIB + 256;
  u16* yi2 = (u16*)p;  p += XIB + 256;
  u16* yi3 = (u16*)p;  p += XIB + 256;
  u16* yi4 = (u16*)p;  p += XIB + 256;
  float* ubuf = (float*)p;             p += (size_t)NN * BB * UU * 4;
  int*   cols = (int*)p;               p += 2 * (size_t)NN * CAP * 4;
  float* vals = (float*)p;             p += 2 * (size_t)NN * CAP * 4;
  int*   nnzA = (int*)p;               p += 2 * (size_t)NN * 4;
  u16*   Wf   = (u16*)p;               p += (size_t)WF_G * 2;
  u16*   W2f  = (u16*)p;               p += (size_t)WF_C * 2;

  // fused prologue: prep_w | extract_csr | build_x0
  prologue<<<PW_BLK + 2048 + NN, 256, 0, stream>>>(
      W, W2, Wf, W2f, S0, S1, cols, vals, nnzA, inp, hx, xi0, bufA);

  // gconv1 hop1: both supports (shared source; xi tails)
  spmm_panel<<<dim3(10240, 2), 128, 0, stream>>>(cols, vals, nnzA,
      xi0, bufA, xi0, bufA, 0, yi1, bufB, yi3, bufD);
  // gconv1 hop2: both supports
  spmm_panel<<<dim3(10240, 2), 128, 0, stream>>>(cols, vals, nnzA,
      yi1, bufB, yi3, bufD, 0, yi2, bufC, yi4, bufE);

  // gate: writes xh' in place into bufA, u -> ubuf (xi frags read inline)
  gate_mfma<<<NN, 256, 0, stream>>>(xi0, yi1, yi2, yi3, yi4,
                                    bufA, bufB, bufC, bufD, bufE,
                                    Wf, bias, hx, bufA, ubuf);

  // gconv2 on xh' (xi mats unchanged; no xi tail)
  spmm_panel<<<dim3(8192, 2), 128, 0, stream>>>(cols, vals, nnzA,
      xi0, bufA, xi0, bufA, 0, yi1, bufB, yi3, bufD);
  spmm_panel<<<dim3(8192, 2), 128, 0, stream>>>(cols, vals, nnzA,
      yi1, bufB, yi3, bufD, 0, yi2, bufC, yi4, bufE);

  // candidate + final combine
  cand_mfma<<<NN, 256, 0, stream>>>(xi0, yi1, yi2, yi3, yi4,
                                    bufA, bufB, bufC, bufD, bufE,
                                    W2f, b2, hx, ubuf, out);
}

// Round 11
// 545.063 us; speedup vs baseline: 1.0610x; 1.0043x over previous
//
#include <hip/hip_runtime.h>
#include <math.h>

// DCGRU cell, N=4096, B=32, U=64, F=66, M=5, 2 supports.
// R22: R21 + spmm fma-path via v_dot2_f32_bf16 (2 bf16 MACs/instr): per nnz
// PAIR, 8 v_perm (interleave x_k[j],x_k+1[j]) + 8 dot2 replaces 16 unpack +
// 16 fma (~40% VALU cut on the dominant path; R13 showed spmm VALU is near-
// binding: +80% VALU cycles -> +23% time). Entire path gated on
// __has_builtin(__builtin_amdgcn_fdot2_f32_bf16): absent -> byte-identical
// to R21 (safe neutral). vals bf16-rounded only inside the dot path.
// Everything else untouched (R21 = 547.4us best: R12 spmm, R18 gate/cand,
// vectorized fused prologue).

#define NN 4096
#define BB 32
#define UU 64
#define FF 66
#define MM 5
#define XHC 2048       // xh row elements (4096 B)
#define XIC 64         // xi row elements (128 B)
#define CAP 128        // max nnz/row, padded to %8 (min 16)
#define CHUNK 4
#define WF_G (8*11*64*8)
#define WF_C (4*11*64*8)
#define PW_BLK ((WF_G + WF_C + 255) / 256)   // 264

typedef unsigned short u16;
typedef __attribute__((ext_vector_type(8))) short short8;
typedef __attribute__((ext_vector_type(4))) float float4v;

__device__ __forceinline__ u16 f2bf(float f) {
  unsigned u = __float_as_uint(f);
  u += 0x7FFFu + ((u >> 16) & 1u);   // RNE
  return (u16)(u >> 16);
}
__device__ __forceinline__ unsigned pack2(float lo, float hi) {
  return (unsigned)f2bf(lo) | ((unsigned)f2bf(hi) << 16);
}
__device__ __forceinline__ float bflo(unsigned d) { return __uint_as_float(d << 16); }
__device__ __forceinline__ float bfhi(unsigned d) { return __uint_as_float(d & 0xFFFF0000u); }
__device__ __forceinline__ float bf1(u16 v) { return __uint_as_float((unsigned)v << 16); }

__device__ __forceinline__ float sigmoidf_(float x) {
  return 1.0f / (1.0f + __expf(-x));
}
__device__ __forceinline__ float tanhf_(float x) {
  x = fminf(fmaxf(x, -15.f), 15.f);
  float e = __expf(2.f * x);
  return (e - 1.f) / (e + 1.f);
}

// ---------------- weight fold helper ----------------------------------------
__device__ __forceinline__ float wfold(const float* W, int f, int m, int o, int O) {
  if (m == 0)
    return W[((size_t)f * MM + 0) * O + o] - W[((size_t)f * MM + 2) * O + o]
         - W[((size_t)f * MM + 4) * O + o];
  float v = W[((size_t)f * MM + m) * O + o];
  return (m == 2 || m == 4) ? 2.0f * v : v;
}

// ---------------- fused prologue: prep_w | extract_csr | build_x0 -----------
__global__ __launch_bounds__(256) void prologue(
    const float* __restrict__ W, const float* __restrict__ W2,
    u16* __restrict__ Wf, u16* __restrict__ W2f,
    const float* __restrict__ S0, const float* __restrict__ S1,
    int* __restrict__ cols, float* __restrict__ vals, int* __restrict__ nnz,
    const float* __restrict__ inp, const float* __restrict__ hx,
    u16* __restrict__ xi0, u16* __restrict__ xh0) {
  int bid = blockIdx.x;
  if (bid < PW_BLK) {
    // ---- prep_w: Chebyshev fold + k-scan fragment order ----
    int idx = bid * 256 + threadIdx.x;
    if (idx < WF_G) {
      int j = idx & 7, lane = (idx >> 3) & 63, q = idx >> 9;
      int ks = q % 11, t = q / 11;
      int o = t * 16 + (lane & 15);
      int qj = (lane >> 4) * 8 + j;
      float v = 0.f;
      if (ks < 10)      { v = wfold(W, 2 + (ks & 1) * 32 + qj, ks >> 1, o, 128); }
      else if (qj < 10) { v = wfold(W, qj & 1, qj >> 1, o, 128); }
      Wf[idx] = f2bf(v);
    } else if (idx < WF_G + WF_C) {
      int i2 = idx - WF_G;
      int j = i2 & 7, lane = (i2 >> 3) & 63, q = i2 >> 9;
      int ks = q % 11, t = q / 11;
      int o = t * 16 + (lane & 15);
      int qj = (lane >> 4) * 8 + j;
      float v = 0.f;
      if (ks < 10)      { v = wfold(W2, 2 + (ks & 1) * 32 + qj, ks >> 1, o, UU); }
      else if (qj < 10) { v = wfold(W2, qj & 1, qj >> 1, o, UU); }
      W2f[i2] = f2bf(v);
    }
  } else if (bid < PW_BLK + 2048) {
    // ---- extract_csr: float4 scan, order-preserving compaction ----
    int e = bid - PW_BLK;
    int sup = e >> 10;
    int bx  = e & 1023;
    int wave = threadIdx.x >> 6;
    int lane = threadIdx.x & 63;
    int row  = bx * 4 + wave;
    const float4* srow4 = (const float4*)((sup ? S1 : S0) + (size_t)row * NN);
    int*   crow = cols + ((size_t)sup * NN + row) * CAP;
    float* vrow = vals + ((size_t)sup * NN + row) * CAP;
    unsigned long long below = (1ull << lane) - 1ull;
    int base = 0;
    for (int it = 0; it < NN / 256; ++it) {        // 16 chunks of 256 cols
      float4 v = srow4[it * 64 + lane];
      unsigned long long m0 = __ballot(v.x != 0.0f);
      unsigned long long m1 = __ballot(v.y != 0.0f);
      unsigned long long m2 = __ballot(v.z != 0.0f);
      unsigned long long m3 = __ballot(v.w != 0.0f);
      int pos = base + __popcll(m0 & below) + __popcll(m1 & below)
                     + __popcll(m2 & below) + __popcll(m3 & below);
      int c0 = it * 256 + lane * 4;
      if (v.x != 0.0f) { if (pos < CAP) { crow[pos] = c0;     vrow[pos] = v.x; } ++pos; }
      if (v.y != 0.0f) { if (pos < CAP) { crow[pos] = c0 + 1; vrow[pos] = v.y; } ++pos; }
      if (v.z != 0.0f) { if (pos < CAP) { crow[pos] = c0 + 2; vrow[pos] = v.z; } ++pos; }
      if (v.w != 0.0f) { if (pos < CAP) { crow[pos] = c0 + 3; vrow[pos] = v.w; } ++pos; }
      base += __popcll(m0) + __popcll(m1) + __popcll(m2) + __popcll(m3);
    }
    if (base > CAP) base = CAP;
    int padded = (base + 7) & ~7;
    if (padded < 16) padded = 16;
    if (padded > CAP) padded = CAP;
    int p = base + lane;
    if (p < padded) { crow[p] = 0; vrow[p] = 0.0f; }
    if (lane == 0) nnz[sup * NN + row] = padded;
  } else {
    // ---- build_x0: float4 hx reads ----
    int n = bid - PW_BLK - 2048;
    unsigned* xhd = (unsigned*)(xh0 + (size_t)n * XHC);
    for (int j = threadIdx.x; j < XHC / 4; j += 256) {   // 512 jobs x 4 floats
      int b = j >> 4, f4 = (j & 15) * 4;
      float4 h = *(const float4*)(hx + (size_t)b * (NN * UU) + (size_t)n * UU + f4);
      xhd[j * 2]     = pack2(h.x, h.y);
      xhd[j * 2 + 1] = pack2(h.z, h.w);
    }
    if (threadIdx.x < 32) {
      int b = threadIdx.x;
      unsigned* xid = (unsigned*)(xi0 + (size_t)n * XIC);
      xid[b] = pack2(inp[(size_t)b * (NN * 2) + n * 2],
                     inp[(size_t)b * (NN * 2) + n * 2 + 1]);
    }
  }
}

// ---------------- SpMM: y = S@x. 4x1KB panels, VGPR gather, dbuf (R12) ------
__device__ __forceinline__ void fma8(float v, uint4 q, float* a) {
  a[0] = fmaf(v, bflo(q.x), a[0]); a[1] = fmaf(v, bfhi(q.x), a[1]);
  a[2] = fmaf(v, bflo(q.y), a[2]); a[3] = fmaf(v, bfhi(q.y), a[3]);
  a[4] = fmaf(v, bflo(q.z), a[4]); a[5] = fmaf(v, bfhi(q.z), a[5]);
  a[6] = fmaf(v, bflo(q.w), a[6]); a[7] = fmaf(v, bfhi(q.w), a[7]);
}

__device__ __forceinline__ void loadC4(uint4* q, const int* crow, int k0,
                                       const u16* gpan, int lane) {
#pragma unroll
  for (int i = 0; i < CHUNK; ++i) {
    int c = crow[k0 + i];                             // scalar (s_load)
    q[i] = *(const uint4*)(gpan + ((size_t)c << 11) + (lane << 3));
  }
}

#if __has_builtin(__builtin_amdgcn_fdot2_f32_bf16)
typedef __attribute__((ext_vector_type(2))) __bf16 bf16x2;
__device__ __forceinline__ bf16x2 as_bf16x2(unsigned u) {
  union { unsigned u; bf16x2 v; } c; c.u = u; return c.v;
}
// nnz pair (2p, 2p+1): 8 v_perm + 8 v_dot2_f32_bf16 replaces 16 unpack+16 fma
__device__ __forceinline__ void dotP(const uint4* q, const float* vv, int p,
                                     float* a) {
  bf16x2 v2 = as_bf16x2(pack2(vv[2 * p], vv[2 * p + 1]));
  const unsigned* qa = (const unsigned*)&q[2 * p];      // nnz 2p
  const unsigned* qb = (const unsigned*)&q[2 * p + 1];  // nnz 2p+1
#pragma unroll
  for (int d = 0; d < 4; ++d) {
    // lo: (lo16(qa[d]), lo16(qb[d])) ; hi: (hi16(qa[d]), hi16(qb[d]))
    unsigned lo = __builtin_amdgcn_perm(qb[d], qa[d], 0x05040100u);
    unsigned hi = __builtin_amdgcn_perm(qb[d], qa[d], 0x07060302u);
    a[2 * d]     = __builtin_amdgcn_fdot2_f32_bf16(as_bf16x2(lo), v2,
                                                   a[2 * d], false);
    a[2 * d + 1] = __builtin_amdgcn_fdot2_f32_bf16(as_bf16x2(hi), v2,
                                                   a[2 * d + 1], false);
  }
}
__device__ __forceinline__ void fmaC(const uint4* q, const float* vv, float* a) {
  dotP(q, vv, 0, a);
  dotP(q, vv, 1, a);
}
#else
__device__ __forceinline__ void fmaC(const uint4* q, const float* vv, float* a) {
#pragma unroll
  for (int i = 0; i < CHUNK; ++i) fma8(vv[i], q[i], a);
}
#endif

__global__ __launch_bounds__(128) void spmm_panel(
    const int* __restrict__ cols, const float* __restrict__ vals,
    const int* __restrict__ nnz,
    const u16* xiA, const u16* xhA, const u16* xiB, const u16* xhB,
    int sup_base,
    u16* yiA, u16* yhA, u16* yiB, u16* yhB) {
  int bx = blockIdx.x;
  int lane = threadIdx.x & 63;
  int wv = threadIdx.x >> 6;
  int sup = sup_base + blockIdx.y;

  if (bx < 8192) {
    int panel = bx & 3;
    int row = (bx >> 2) * 2 + wv;
    int srow = __builtin_amdgcn_readfirstlane(sup * NN + row);
    const u16* xh = blockIdx.y ? xhB : xhA;
    u16* yh = blockIdx.y ? yhB : yhA;
    const int*   crow = cols + (size_t)srow * CAP;
    const float* vrow = vals + (size_t)srow * CAP;
    int cnt = nnz[srow];
    int nch = cnt >> 2;                 // even (cnt % 8 == 0), >= 4
    const u16* gpan = xh + panel * 512;
    float a[8] = {0.f,0.f,0.f,0.f,0.f,0.f,0.f,0.f};

    uint4 qA[CHUNK], qB[CHUNK];
    loadC4(qA, crow, 0,     gpan, lane);
    loadC4(qB, crow, CHUNK, gpan, lane);
    float vvA[CHUNK], vvB[CHUNK];
#pragma unroll
    for (int i = 0; i < CHUNK; ++i) {
      vvA[i] = vrow[i];
      vvB[i] = vrow[CHUNK + i];
    }

    int c2 = 0;
    for (; c2 + 2 < nch; c2 += 2) {
      float vvA2[CHUNK], vvB2[CHUNK];
#pragma unroll
      for (int i = 0; i < CHUNK; ++i) {
        vvA2[i] = vrow[(c2 + 2) * CHUNK + i];
        vvB2[i] = vrow[(c2 + 3) * CHUNK + i];
      }
      fmaC(qA, vvA, a);
      loadC4(qA, crow, (c2 + 2) * CHUNK, gpan, lane);
      fmaC(qB, vvB, a);
      loadC4(qB, crow, (c2 + 3) * CHUNK, gpan, lane);
#pragma unroll
      for (int i = 0; i < CHUNK; ++i) { vvA[i] = vvA2[i]; vvB[i] = vvB2[i]; }
    }
    fmaC(qA, vvA, a);
    fmaC(qB, vvB, a);

    size_t oh = (size_t)row * XHC + panel * 512 + lane * 8;
    uint4 o4;
    o4.x = pack2(a[0], a[1]); o4.y = pack2(a[2], a[3]);
    o4.z = pack2(a[4], a[5]); o4.w = pack2(a[6], a[7]);
    __builtin_nontemporal_store(o4.x, (unsigned*)(yh + oh));
    __builtin_nontemporal_store(o4.y, (unsigned*)(yh + oh) + 1);
    __builtin_nontemporal_store(o4.z, (unsigned*)(yh + oh) + 2);
    __builtin_nontemporal_store(o4.w, (unsigned*)(yh + oh) + 3);
  } else {
    int row = (bx - 8192) * 2 + wv;
    int srow = __builtin_amdgcn_readfirstlane(sup * NN + row);
    const u16* xs = blockIdx.y ? xiB : xiA;
    u16* yo = blockIdx.y ? yiB : yiA;
    const int*   crow = cols + (size_t)srow * CAP;
    const float* vrow = vals + (size_t)srow * CAP;
    int cnt = nnz[srow];
    float a = 0.f;
    for (int k0 = 0; k0 < cnt; k0 += 8) {
      int cc[8]; float vv[8];
#pragma unroll
      for (int i = 0; i < 8; ++i) { cc[i] = crow[k0 + i]; vv[i] = vrow[k0 + i]; }
      u16 q[8];
#pragma unroll
      for (int i = 0; i < 8; ++i) q[i] = xs[(size_t)cc[i] * XIC + lane];
#pragma unroll
      for (int i = 0; i < 8; ++i) a = fmaf(vv[i], bf1(q[i]), a);
    }
    yo[(size_t)row * XIC + lane] = f2bf(a);
  }
}

// ---------------- xi A-fragment, inlined ------------------------------------
// af element j (j=0..7) is k = quad*8+j of the 32-k xi scan:
//   k in [0,10): mat m=k>>1, half f=k&1, value xi_m[n][b*2+f]; k>=10: zero.
__device__ __forceinline__ short8 xi_frag(
    const u16* xi0, const u16* yi1, const u16* yi2, const u16* yi3,
    const u16* yi4, int n, int b, int quad) {
  unsigned a0 = 0, a1 = 0, a2 = 0, a3 = 0;
  size_t off = (size_t)n * 32 + b;
  if (quad == 0) {
    a0 = ((const unsigned*)xi0)[off];
    a1 = ((const unsigned*)yi1)[off];
    a2 = ((const unsigned*)yi2)[off];
    a3 = ((const unsigned*)yi3)[off];
  } else if (quad == 1) {
    a0 = ((const unsigned*)yi4)[off];
  }
  short8 af;
  ((unsigned*)&af)[0] = a0;
  ((unsigned*)&af)[1] = a1;
  ((unsigned*)&af)[2] = a2;
  ((unsigned*)&af)[3] = a3;
  return af;
}

// ---------------- gate: 256 thr, wave = (Mtile, 4 N-tiles) (R18) ------------
__global__ __launch_bounds__(256) void gate_mfma(
    const u16* __restrict__ xi0, const u16* __restrict__ yi1,
    const u16* __restrict__ yi2, const u16* __restrict__ yi3,
    const u16* __restrict__ yi4,
    const u16* h0, const u16* __restrict__ h1, const u16* __restrict__ h2,
    const u16* __restrict__ h3, const u16* __restrict__ h4,
    const u16* __restrict__ Wf, const float* __restrict__ bias,
    const float* __restrict__ hx,
    u16* xhp, float* __restrict__ ubuf) {
  __shared__ u16 lt[BB * UU];           // r*hx staging for coalesced writeback
  int n = blockIdx.x;
  int lane = threadIdx.x & 63;
  int w = threadIdx.x >> 6;
  int Mtile = w & 1;
  int Nbase = (w >> 1) * 4;
  int colo = lane & 15;
  int quad = lane >> 4;
  const u16* hm[5] = {h0, h1, h2, h3, h4};
  float4v acc[4];
#pragma unroll
  for (int t = 0; t < 4; ++t) {
    float bv = bias[(Nbase + t) * 16 + colo];
    acc[t] = (float4v){bv, bv, bv, bv};
  }
  int aoff = (Mtile * 16 + colo) * 64 + quad * 8;  // within an xh row
#pragma unroll
  for (int ks = 0; ks < 10; ++ks) {
    short8 af = *(const short8*)(hm[ks >> 1] + (size_t)n * XHC + aoff + (ks & 1) * 32);
#pragma unroll
    for (int t = 0; t < 4; ++t) {
      short8 bf = *(const short8*)(Wf + (size_t)(((Nbase + t) * 11 + ks) * 64 + lane) * 8);
      acc[t] = __builtin_amdgcn_mfma_f32_16x16x32_bf16(af, bf, acc[t], 0, 0, 0);
    }
  }
  {
    short8 af = xi_frag(xi0, yi1, yi2, yi3, yi4, n, Mtile * 16 + colo, quad);
#pragma unroll
    for (int t = 0; t < 4; ++t) {
      short8 bf = *(const short8*)(Wf + (size_t)(((Nbase + t) * 11 + 10) * 64 + lane) * 8);
      acc[t] = __builtin_amdgcn_mfma_f32_16x16x32_bf16(af, bf, acc[t], 0, 0, 0);
    }
  }
  int brow0 = Mtile * 16 + quad * 4;
#pragma unroll
  for (int t = 0; t < 4; ++t) {
    int o = (Nbase + t) * 16 + colo;
#pragma unroll
    for (int r = 0; r < 4; ++r) {
      int b = brow0 + r;
      float s = sigmoidf_(acc[t][r]);
      if (o < UU) {
        float h = hx[(size_t)b * (NN * UU) + (size_t)n * UU + o];
        lt[b * UU + o] = f2bf(s * h);
      } else {
        ubuf[(size_t)n * (BB * UU) + b * UU + (o - UU)] = s;
      }
    }
  }
  __syncthreads();
  unsigned* xrow = (unsigned*)(xhp + (size_t)n * XHC);
  const unsigned* ltd = (const unsigned*)lt;
  for (int j = threadIdx.x; j < XHC / 2; j += 256)
    xrow[j] = ltd[j];
}

// ---------------- candidate: 256 thr, wave = (Mtile, 2 N-tiles) (R18) -------
__global__ __launch_bounds__(256) void cand_mfma(
    const u16* __restrict__ xi0, const u16* __restrict__ yi1,
    const u16* __restrict__ yi2, const u16* __restrict__ yi3,
    const u16* __restrict__ yi4,
    const u16* __restrict__ h0, const u16* __restrict__ h1,
    const u16* __restrict__ h2, const u16* __restrict__ h3,
    const u16* __restrict__ h4,
    const u16* __restrict__ W2f, const float* __restrict__ b2,
    const float* __restrict__ hx, const float* __restrict__ ubuf,
    float* __restrict__ out) {
  int n = blockIdx.x;
  int lane = threadIdx.x & 63;
  int w = threadIdx.x >> 6;
  int Mtile = w & 1;
  int Nbase = (w >> 1) * 2;
  int colo = lane & 15;
  int quad = lane >> 4;
  const u16* hm[5] = {h0, h1, h2, h3, h4};
  float4v acc[2];
#pragma unroll
  for (int t = 0; t < 2; ++t) {
    float bv = b2[(Nbase + t) * 16 + colo];
    acc[t] = (float4v){bv, bv, bv, bv};
  }
  int aoff = (Mtile * 16 + colo) * 64 + quad * 8;
#pragma unroll
  for (int ks = 0; ks < 10; ++ks) {
    short8 af = *(const short8*)(hm[ks >> 1] + (size_t)n * XHC + aoff + (ks & 1) * 32);
#pragma unroll
    for (int t = 0; t < 2; ++t) {
      short8 bf = *(const short8*)(W2f + (size_t)(((Nbase + t) * 11 + ks) * 64 + lane) * 8);
      acc[t] = __builtin_amdgcn_mfma_f32_16x16x32_bf16(af, bf, acc[t], 0, 0, 0);
    }
  }
  {
    short8 af = xi_frag(xi0, yi1, yi2, yi3, yi4, n, Mtile * 16 + colo, quad);
#pragma unroll
    for (int t = 0; t < 2; ++t) {
      short8 bf = *(const short8*)(W2f + (size_t)(((Nbase + t) * 11 + 10) * 64 + lane) * 8);
      acc[t] = __builtin_amdgcn_mfma_f32_16x16x32_bf16(af, bf, acc[t], 0, 0, 0);
    }
  }
  int brow0 = Mtile * 16 + quad * 4;
#pragma unroll
  for (int t = 0; t < 2; ++t) {
    int o = (Nbase + t) * 16 + colo;
#pragma unroll
    for (int r = 0; r < 4; ++r) {
      int b = brow0 + r;
      float c = tanhf_(acc[t][r]);
      float u = ubuf[(size_t)n * (BB * UU) + b * UU + o];
      float h = hx[(size_t)b * (NN * UU) + (size_t)n * UU + o];
      out[(size_t)b * (NN * UU) + (size_t)n * UU + o] = u * h + (1.0f - u) * c;
    }
  }
}

extern "C" void kernel_launch(void* const* d_in, const int* in_sizes, int n_in,
                              void* d_out, int out_size, void* d_ws, size_t ws_size,
                              hipStream_t stream) {
  const float* inp  = (const float*)d_in[0];
  const float* hx   = (const float*)d_in[1];
  const float* S0   = (const float*)d_in[2];
  const float* S1   = (const float*)d_in[3];
  const float* W    = (const float*)d_in[4];
  const float* bias = (const float*)d_in[5];
  const float* W2   = (const float*)d_in[6];
  const float* b2   = (const float*)d_in[7];
  float* out = (float*)d_out;

  char* ws = (char*)d_ws;
  const size_t XHB = (size_t)NN * XHC * sizeof(u16);
  const size_t XIB = (size_t)NN * XIC * sizeof(u16);
  u16* bufA = (u16*)(ws);              // xh0 -> xh'
  u16* bufB = (u16*)(ws + 1 * XHB);    // S0@x
  u16* bufC = (u16*)(ws + 2 * XHB);    // S0@S0@x
  u16* bufD = (u16*)(ws + 3 * XHB);    // S1@x
  u16* bufE = (u16*)(ws + 4 * XHB);    // S1@S1@x
  char* p = ws + 5 * XHB;
  u16* xi0 = (u16*)p;  p += XIB + 256;
  u16* yi1 = (u16*)p;  p += XIB + 256;
  u16* yi2 = (u16*)p;  p += XIB + 256;
  u16* yi3 = (u16*)p;  p += XIB + 256;
  u16* yi4 = (u16*)p;  p += XIB + 256;
  float* ubuf = (float*)p;             p += (size_t)NN * BB * UU * 4;
  int*   cols = (int*)p;               p += 2 * (size_t)NN * CAP * 4;
  float* vals = (float*)p;             p += 2 * (size_t)NN * CAP * 4;
  int*   nnzA = (int*)p;               p += 2 * (size_t)NN * 4;
  u16*   Wf   = (u16*)p;               p += (size_t)WF_G * 2;
  u16*   W2f  = (u16*)p;               p += (size_t)WF_C * 2;

  // fused prologue: prep_w | extract_csr | build_x0
  prologue<<<PW_BLK + 2048 + NN, 256, 0, stream>>>(
      W, W2, Wf, W2f, S0, S1, cols, vals, nnzA, inp, hx, xi0, bufA);

  // gconv1 hop1: both supports (shared source; xi tails)
  spmm_panel<<<dim3(10240, 2), 128, 0, stream>>>(cols, vals, nnzA,
      xi0, bufA, xi0, bufA, 0, yi1, bufB, yi3, bufD);
  // gconv1 hop2: both supports
  spmm_panel<<<dim3(10240, 2), 128, 0, stream>>>(cols, vals, nnzA,
      yi1, bufB, yi3, bufD, 0, yi2, bufC, yi4, bufE);

  // gate: writes xh' in place into bufA, u -> ubuf (xi frags read inline)
  gate_mfma<<<NN, 256, 0, stream>>>(xi0, yi1, yi2, yi3, yi4,
                                    bufA, bufB, bufC, bufD, bufE,
                                    Wf, bias, hx, bufA, ubuf);

  // gconv2 on xh' (xi mats unchanged; no xi tail)
  spmm_panel<<<dim3(8192, 2), 128, 0, stream>>>(cols, vals, nnzA,
      xi0, bufA, xi0, bufA, 0, yi1, bufB, yi3, bufD);
  spmm_panel<<<dim3(8192, 2), 128, 0, stream>>>(cols, vals, nnzA,
      yi1, bufB, yi3, bufD, 0, yi2, bufC, yi4, bufE);

  // candidate + final combine
  cand_mfma<<<NN, 256, 0, stream>>>(xi0, yi1, yi2, yi3, yi4,
                                    bufA, bufB, bufC, bufD, bufE,
                                    W2f, b2, hx, ubuf, out);
}

// Round 12
// 542.887 us; speedup vs baseline: 1.0653x; 1.0040x over previous
//
#include <hip/hip_runtime.h>
#include <math.h>

// DCGRU cell, N=4096, B=32, U=64, F=66, M=5, 2 supports.
// R23: R22 + gate reads r*hx's h from bufA (bf16, [n][b*64+o], L2-hot: the
// SAME rows this block just read as A-frags) instead of 32MB of scattered
// b-major fp32 hx loads (a ~700cy L3 tail per block, post-MFMA, pre-barrier).
// xh' was f2bf(s*h) already -> f2bf(s*bf16(h)) is <=1 extra ulp. cand's
// final-combine keeps the fp32 hx read (feeds output directly). R22 spmm
// dot2 kept (VALU 48->36%, occ 68%, dur ~72.5: proved spmm is pinned at the
// ~20 TB/s random-gather L2 service envelope - closed). R21 prologue kept.

#define NN 4096
#define BB 32
#define UU 64
#define FF 66
#define MM 5
#define XHC 2048       // xh row elements (4096 B)
#define XIC 64         // xi row elements (128 B)
#define CAP 128        // max nnz/row, padded to %8 (min 16)
#define CHUNK 4
#define WF_G (8*11*64*8)
#define WF_C (4*11*64*8)
#define PW_BLK ((WF_G + WF_C + 255) / 256)   // 264

typedef unsigned short u16;
typedef __attribute__((ext_vector_type(8))) short short8;
typedef __attribute__((ext_vector_type(4))) float float4v;

__device__ __forceinline__ u16 f2bf(float f) {
  unsigned u = __float_as_uint(f);
  u += 0x7FFFu + ((u >> 16) & 1u);   // RNE
  return (u16)(u >> 16);
}
__device__ __forceinline__ unsigned pack2(float lo, float hi) {
  return (unsigned)f2bf(lo) | ((unsigned)f2bf(hi) << 16);
}
__device__ __forceinline__ float bflo(unsigned d) { return __uint_as_float(d << 16); }
__device__ __forceinline__ float bfhi(unsigned d) { return __uint_as_float(d & 0xFFFF0000u); }
__device__ __forceinline__ float bf1(u16 v) { return __uint_as_float((unsigned)v << 16); }

__device__ __forceinline__ float sigmoidf_(float x) {
  return 1.0f / (1.0f + __expf(-x));
}
__device__ __forceinline__ float tanhf_(float x) {
  x = fminf(fmaxf(x, -15.f), 15.f);
  float e = __expf(2.f * x);
  return (e - 1.f) / (e + 1.f);
}

// ---------------- weight fold helper ----------------------------------------
__device__ __forceinline__ float wfold(const float* W, int f, int m, int o, int O) {
  if (m == 0)
    return W[((size_t)f * MM + 0) * O + o] - W[((size_t)f * MM + 2) * O + o]
         - W[((size_t)f * MM + 4) * O + o];
  float v = W[((size_t)f * MM + m) * O + o];
  return (m == 2 || m == 4) ? 2.0f * v : v;
}

// ---------------- fused prologue: prep_w | extract_csr | build_x0 -----------
__global__ __launch_bounds__(256) void prologue(
    const float* __restrict__ W, const float* __restrict__ W2,
    u16* __restrict__ Wf, u16* __restrict__ W2f,
    const float* __restrict__ S0, const float* __restrict__ S1,
    int* __restrict__ cols, float* __restrict__ vals, int* __restrict__ nnz,
    const float* __restrict__ inp, const float* __restrict__ hx,
    u16* __restrict__ xi0, u16* __restrict__ xh0) {
  int bid = blockIdx.x;
  if (bid < PW_BLK) {
    // ---- prep_w: Chebyshev fold + k-scan fragment order ----
    int idx = bid * 256 + threadIdx.x;
    if (idx < WF_G) {
      int j = idx & 7, lane = (idx >> 3) & 63, q = idx >> 9;
      int ks = q % 11, t = q / 11;
      int o = t * 16 + (lane & 15);
      int qj = (lane >> 4) * 8 + j;
      float v = 0.f;
      if (ks < 10)      { v = wfold(W, 2 + (ks & 1) * 32 + qj, ks >> 1, o, 128); }
      else if (qj < 10) { v = wfold(W, qj & 1, qj >> 1, o, 128); }
      Wf[idx] = f2bf(v);
    } else if (idx < WF_G + WF_C) {
      int i2 = idx - WF_G;
      int j = i2 & 7, lane = (i2 >> 3) & 63, q = i2 >> 9;
      int ks = q % 11, t = q / 11;
      int o = t * 16 + (lane & 15);
      int qj = (lane >> 4) * 8 + j;
      float v = 0.f;
      if (ks < 10)      { v = wfold(W2, 2 + (ks & 1) * 32 + qj, ks >> 1, o, UU); }
      else if (qj < 10) { v = wfold(W2, qj & 1, qj >> 1, o, UU); }
      W2f[i2] = f2bf(v);
    }
  } else if (bid < PW_BLK + 2048) {
    // ---- extract_csr: float4 scan, order-preserving compaction ----
    int e = bid - PW_BLK;
    int sup = e >> 10;
    int bx  = e & 1023;
    int wave = threadIdx.x >> 6;
    int lane = threadIdx.x & 63;
    int row  = bx * 4 + wave;
    const float4* srow4 = (const float4*)((sup ? S1 : S0) + (size_t)row * NN);
    int*   crow = cols + ((size_t)sup * NN + row) * CAP;
    float* vrow = vals + ((size_t)sup * NN + row) * CAP;
    unsigned long long below = (1ull << lane) - 1ull;
    int base = 0;
    for (int it = 0; it < NN / 256; ++it) {        // 16 chunks of 256 cols
      float4 v = srow4[it * 64 + lane];
      unsigned long long m0 = __ballot(v.x != 0.0f);
      unsigned long long m1 = __ballot(v.y != 0.0f);
      unsigned long long m2 = __ballot(v.z != 0.0f);
      unsigned long long m3 = __ballot(v.w != 0.0f);
      int pos = base + __popcll(m0 & below) + __popcll(m1 & below)
                     + __popcll(m2 & below) + __popcll(m3 & below);
      int c0 = it * 256 + lane * 4;
      if (v.x != 0.0f) { if (pos < CAP) { crow[pos] = c0;     vrow[pos] = v.x; } ++pos; }
      if (v.y != 0.0f) { if (pos < CAP) { crow[pos] = c0 + 1; vrow[pos] = v.y; } ++pos; }
      if (v.z != 0.0f) { if (pos < CAP) { crow[pos] = c0 + 2; vrow[pos] = v.z; } ++pos; }
      if (v.w != 0.0f) { if (pos < CAP) { crow[pos] = c0 + 3; vrow[pos] = v.w; } ++pos; }
      base += __popcll(m0) + __popcll(m1) + __popcll(m2) + __popcll(m3);
    }
    if (base > CAP) base = CAP;
    int padded = (base + 7) & ~7;
    if (padded < 16) padded = 16;
    if (padded > CAP) padded = CAP;
    int p = base + lane;
    if (p < padded) { crow[p] = 0; vrow[p] = 0.0f; }
    if (lane == 0) nnz[sup * NN + row] = padded;
  } else {
    // ---- build_x0: float4 hx reads ----
    int n = bid - PW_BLK - 2048;
    unsigned* xhd = (unsigned*)(xh0 + (size_t)n * XHC);
    for (int j = threadIdx.x; j < XHC / 4; j += 256) {   // 512 jobs x 4 floats
      int b = j >> 4, f4 = (j & 15) * 4;
      float4 h = *(const float4*)(hx + (size_t)b * (NN * UU) + (size_t)n * UU + f4);
      xhd[j * 2]     = pack2(h.x, h.y);
      xhd[j * 2 + 1] = pack2(h.z, h.w);
    }
    if (threadIdx.x < 32) {
      int b = threadIdx.x;
      unsigned* xid = (unsigned*)(xi0 + (size_t)n * XIC);
      xid[b] = pack2(inp[(size_t)b * (NN * 2) + n * 2],
                     inp[(size_t)b * (NN * 2) + n * 2 + 1]);
    }
  }
}

// ---------------- SpMM: y = S@x. 4x1KB panels, VGPR gather, dbuf (R12) ------
__device__ __forceinline__ void fma8(float v, uint4 q, float* a) {
  a[0] = fmaf(v, bflo(q.x), a[0]); a[1] = fmaf(v, bfhi(q.x), a[1]);
  a[2] = fmaf(v, bflo(q.y), a[2]); a[3] = fmaf(v, bfhi(q.y), a[3]);
  a[4] = fmaf(v, bflo(q.z), a[4]); a[5] = fmaf(v, bfhi(q.z), a[5]);
  a[6] = fmaf(v, bflo(q.w), a[6]); a[7] = fmaf(v, bfhi(q.w), a[7]);
}

__device__ __forceinline__ void loadC4(uint4* q, const int* crow, int k0,
                                       const u16* gpan, int lane) {
#pragma unroll
  for (int i = 0; i < CHUNK; ++i) {
    int c = crow[k0 + i];                             // scalar (s_load)
    q[i] = *(const uint4*)(gpan + ((size_t)c << 11) + (lane << 3));
  }
}

#if __has_builtin(__builtin_amdgcn_fdot2_f32_bf16)
typedef __attribute__((ext_vector_type(2))) __bf16 bf16x2;
__device__ __forceinline__ bf16x2 as_bf16x2(unsigned u) {
  union { unsigned u; bf16x2 v; } c; c.u = u; return c.v;
}
// nnz pair (2p, 2p+1): 8 v_perm + 8 v_dot2_f32_bf16 replaces 16 unpack+16 fma
__device__ __forceinline__ void dotP(const uint4* q, const float* vv, int p,
                                     float* a) {
  bf16x2 v2 = as_bf16x2(pack2(vv[2 * p], vv[2 * p + 1]));
  const unsigned* qa = (const unsigned*)&q[2 * p];      // nnz 2p
  const unsigned* qb = (const unsigned*)&q[2 * p + 1];  // nnz 2p+1
#pragma unroll
  for (int d = 0; d < 4; ++d) {
    // lo: (lo16(qa[d]), lo16(qb[d])) ; hi: (hi16(qa[d]), hi16(qb[d]))
    unsigned lo = __builtin_amdgcn_perm(qb[d], qa[d], 0x05040100u);
    unsigned hi = __builtin_amdgcn_perm(qb[d], qa[d], 0x07060302u);
    a[2 * d]     = __builtin_amdgcn_fdot2_f32_bf16(as_bf16x2(lo), v2,
                                                   a[2 * d], false);
    a[2 * d + 1] = __builtin_amdgcn_fdot2_f32_bf16(as_bf16x2(hi), v2,
                                                   a[2 * d + 1], false);
  }
}
__device__ __forceinline__ void fmaC(const uint4* q, const float* vv, float* a) {
  dotP(q, vv, 0, a);
  dotP(q, vv, 1, a);
}
#else
__device__ __forceinline__ void fmaC(const uint4* q, const float* vv, float* a) {
#pragma unroll
  for (int i = 0; i < CHUNK; ++i) fma8(vv[i], q[i], a);
}
#endif

__global__ __launch_bounds__(128) void spmm_panel(
    const int* __restrict__ cols, const float* __restrict__ vals,
    const int* __restrict__ nnz,
    const u16* xiA, const u16* xhA, const u16* xiB, const u16* xhB,
    int sup_base,
    u16* yiA, u16* yhA, u16* yiB, u16* yhB) {
  int bx = blockIdx.x;
  int lane = threadIdx.x & 63;
  int wv = threadIdx.x >> 6;
  int sup = sup_base + blockIdx.y;

  if (bx < 8192) {
    int panel = bx & 3;
    int row = (bx >> 2) * 2 + wv;
    int srow = __builtin_amdgcn_readfirstlane(sup * NN + row);
    const u16* xh = blockIdx.y ? xhB : xhA;
    u16* yh = blockIdx.y ? yhB : yhA;
    const int*   crow = cols + (size_t)srow * CAP;
    const float* vrow = vals + (size_t)srow * CAP;
    int cnt = nnz[srow];
    int nch = cnt >> 2;                 // even (cnt % 8 == 0), >= 4
    const u16* gpan = xh + panel * 512;
    float a[8] = {0.f,0.f,0.f,0.f,0.f,0.f,0.f,0.f};

    uint4 qA[CHUNK], qB[CHUNK];
    loadC4(qA, crow, 0,     gpan, lane);
    loadC4(qB, crow, CHUNK, gpan, lane);
    float vvA[CHUNK], vvB[CHUNK];
#pragma unroll
    for (int i = 0; i < CHUNK; ++i) {
      vvA[i] = vrow[i];
      vvB[i] = vrow[CHUNK + i];
    }

    int c2 = 0;
    for (; c2 + 2 < nch; c2 += 2) {
      float vvA2[CHUNK], vvB2[CHUNK];
#pragma unroll
      for (int i = 0; i < CHUNK; ++i) {
        vvA2[i] = vrow[(c2 + 2) * CHUNK + i];
        vvB2[i] = vrow[(c2 + 3) * CHUNK + i];
      }
      fmaC(qA, vvA, a);
      loadC4(qA, crow, (c2 + 2) * CHUNK, gpan, lane);
      fmaC(qB, vvB, a);
      loadC4(qB, crow, (c2 + 3) * CHUNK, gpan, lane);
#pragma unroll
      for (int i = 0; i < CHUNK; ++i) { vvA[i] = vvA2[i]; vvB[i] = vvB2[i]; }
    }
    fmaC(qA, vvA, a);
    fmaC(qB, vvB, a);

    size_t oh = (size_t)row * XHC + panel * 512 + lane * 8;
    uint4 o4;
    o4.x = pack2(a[0], a[1]); o4.y = pack2(a[2], a[3]);
    o4.z = pack2(a[4], a[5]); o4.w = pack2(a[6], a[7]);
    __builtin_nontemporal_store(o4.x, (unsigned*)(yh + oh));
    __builtin_nontemporal_store(o4.y, (unsigned*)(yh + oh) + 1);
    __builtin_nontemporal_store(o4.z, (unsigned*)(yh + oh) + 2);
    __builtin_nontemporal_store(o4.w, (unsigned*)(yh + oh) + 3);
  } else {
    int row = (bx - 8192) * 2 + wv;
    int srow = __builtin_amdgcn_readfirstlane(sup * NN + row);
    const u16* xs = blockIdx.y ? xiB : xiA;
    u16* yo = blockIdx.y ? yiB : yiA;
    const int*   crow = cols + (size_t)srow * CAP;
    const float* vrow = vals + (size_t)srow * CAP;
    int cnt = nnz[srow];
    float a = 0.f;
    for (int k0 = 0; k0 < cnt; k0 += 8) {
      int cc[8]; float vv[8];
#pragma unroll
      for (int i = 0; i < 8; ++i) { cc[i] = crow[k0 + i]; vv[i] = vrow[k0 + i]; }
      u16 q[8];
#pragma unroll
      for (int i = 0; i < 8; ++i) q[i] = xs[(size_t)cc[i] * XIC + lane];
#pragma unroll
      for (int i = 0; i < 8; ++i) a = fmaf(vv[i], bf1(q[i]), a);
    }
    yo[(size_t)row * XIC + lane] = f2bf(a);
  }
}

// ---------------- xi A-fragment, inlined ------------------------------------
// af element j (j=0..7) is k = quad*8+j of the 32-k xi scan:
//   k in [0,10): mat m=k>>1, half f=k&1, value xi_m[n][b*2+f]; k>=10: zero.
__device__ __forceinline__ short8 xi_frag(
    const u16* xi0, const u16* yi1, const u16* yi2, const u16* yi3,
    const u16* yi4, int n, int b, int quad) {
  unsigned a0 = 0, a1 = 0, a2 = 0, a3 = 0;
  size_t off = (size_t)n * 32 + b;
  if (quad == 0) {
    a0 = ((const unsigned*)xi0)[off];
    a1 = ((const unsigned*)yi1)[off];
    a2 = ((const unsigned*)yi2)[off];
    a3 = ((const unsigned*)yi3)[off];
  } else if (quad == 1) {
    a0 = ((const unsigned*)yi4)[off];
  }
  short8 af;
  ((unsigned*)&af)[0] = a0;
  ((unsigned*)&af)[1] = a1;
  ((unsigned*)&af)[2] = a2;
  ((unsigned*)&af)[3] = a3;
  return af;
}

// ---------------- gate: 256 thr, wave = (Mtile, 4 N-tiles) (R18) ------------
// R23: r*hx reads h from h0 (= bufA, bf16, [n][b*64+o]) - L2-hot rows this
// block already read as A-frags - instead of 32MB scattered b-major fp32 hx.
__global__ __launch_bounds__(256) void gate_mfma(
    const u16* __restrict__ xi0, const u16* __restrict__ yi1,
    const u16* __restrict__ yi2, const u16* __restrict__ yi3,
    const u16* __restrict__ yi4,
    const u16* h0, const u16* __restrict__ h1, const u16* __restrict__ h2,
    const u16* __restrict__ h3, const u16* __restrict__ h4,
    const u16* __restrict__ Wf, const float* __restrict__ bias,
    u16* xhp, float* __restrict__ ubuf) {
  __shared__ u16 lt[BB * UU];           // r*hx staging for coalesced writeback
  int n = blockIdx.x;
  int lane = threadIdx.x & 63;
  int w = threadIdx.x >> 6;
  int Mtile = w & 1;
  int Nbase = (w >> 1) * 4;
  int colo = lane & 15;
  int quad = lane >> 4;
  const u16* hm[5] = {h0, h1, h2, h3, h4};
  float4v acc[4];
#pragma unroll
  for (int t = 0; t < 4; ++t) {
    float bv = bias[(Nbase + t) * 16 + colo];
    acc[t] = (float4v){bv, bv, bv, bv};
  }
  int aoff = (Mtile * 16 + colo) * 64 + quad * 8;  // within an xh row
#pragma unroll
  for (int ks = 0; ks < 10; ++ks) {
    short8 af = *(const short8*)(hm[ks >> 1] + (size_t)n * XHC + aoff + (ks & 1) * 32);
#pragma unroll
    for (int t = 0; t < 4; ++t) {
      short8 bf = *(const short8*)(Wf + (size_t)(((Nbase + t) * 11 + ks) * 64 + lane) * 8);
      acc[t] = __builtin_amdgcn_mfma_f32_16x16x32_bf16(af, bf, acc[t], 0, 0, 0);
    }
  }
  {
    short8 af = xi_frag(xi0, yi1, yi2, yi3, yi4, n, Mtile * 16 + colo, quad);
#pragma unroll
    for (int t = 0; t < 4; ++t) {
      short8 bf = *(const short8*)(Wf + (size_t)(((Nbase + t) * 11 + 10) * 64 + lane) * 8);
      acc[t] = __builtin_amdgcn_mfma_f32_16x16x32_bf16(af, bf, acc[t], 0, 0, 0);
    }
  }
  int brow0 = Mtile * 16 + quad * 4;
#pragma unroll
  for (int t = 0; t < 4; ++t) {
    int o = (Nbase + t) * 16 + colo;
#pragma unroll
    for (int r = 0; r < 4; ++r) {
      int b = brow0 + r;
      float s = sigmoidf_(acc[t][r]);
      if (o < UU) {
        float h = bf1(h0[(size_t)n * XHC + b * 64 + o]);   // L2-hot bf16 read
        lt[b * UU + o] = f2bf(s * h);
      } else {
        ubuf[(size_t)n * (BB * UU) + b * UU + (o - UU)] = s;
      }
    }
  }
  __syncthreads();
  unsigned* xrow = (unsigned*)(xhp + (size_t)n * XHC);
  const unsigned* ltd = (const unsigned*)lt;
  for (int j = threadIdx.x; j < XHC / 2; j += 256)
    xrow[j] = ltd[j];
}

// ---------------- candidate: 256 thr, wave = (Mtile, 2 N-tiles) (R18) -------
__global__ __launch_bounds__(256) void cand_mfma(
    const u16* __restrict__ xi0, const u16* __restrict__ yi1,
    const u16* __restrict__ yi2, const u16* __restrict__ yi3,
    const u16* __restrict__ yi4,
    const u16* __restrict__ h0, const u16* __restrict__ h1,
    const u16* __restrict__ h2, const u16* __restrict__ h3,
    const u16* __restrict__ h4,
    const u16* __restrict__ W2f, const float* __restrict__ b2,
    const float* __restrict__ hx, const float* __restrict__ ubuf,
    float* __restrict__ out) {
  int n = blockIdx.x;
  int lane = threadIdx.x & 63;
  int w = threadIdx.x >> 6;
  int Mtile = w & 1;
  int Nbase = (w >> 1) * 2;
  int colo = lane & 15;
  int quad = lane >> 4;
  const u16* hm[5] = {h0, h1, h2, h3, h4};
  float4v acc[2];
#pragma unroll
  for (int t = 0; t < 2; ++t) {
    float bv = b2[(Nbase + t) * 16 + colo];
    acc[t] = (float4v){bv, bv, bv, bv};
  }
  int aoff = (Mtile * 16 + colo) * 64 + quad * 8;
#pragma unroll
  for (int ks = 0; ks < 10; ++ks) {
    short8 af = *(const short8*)(hm[ks >> 1] + (size_t)n * XHC + aoff + (ks & 1) * 32);
#pragma unroll
    for (int t = 0; t < 2; ++t) {
      short8 bf = *(const short8*)(W2f + (size_t)(((Nbase + t) * 11 + ks) * 64 + lane) * 8);
      acc[t] = __builtin_amdgcn_mfma_f32_16x16x32_bf16(af, bf, acc[t], 0, 0, 0);
    }
  }
  {
    short8 af = xi_frag(xi0, yi1, yi2, yi3, yi4, n, Mtile * 16 + colo, quad);
#pragma unroll
    for (int t = 0; t < 2; ++t) {
      short8 bf = *(const short8*)(W2f + (size_t)(((Nbase + t) * 11 + 10) * 64 + lane) * 8);
      acc[t] = __builtin_amdgcn_mfma_f32_16x16x32_bf16(af, bf, acc[t], 0, 0, 0);
    }
  }
  int brow0 = Mtile * 16 + quad * 4;
#pragma unroll
  for (int t = 0; t < 2; ++t) {
    int o = (Nbase + t) * 16 + colo;
#pragma unroll
    for (int r = 0; r < 4; ++r) {
      int b = brow0 + r;
      float c = tanhf_(acc[t][r]);
      float u = ubuf[(size_t)n * (BB * UU) + b * UU + o];
      float h = hx[(size_t)b * (NN * UU) + (size_t)n * UU + o];
      out[(size_t)b * (NN * UU) + (size_t)n * UU + o] = u * h + (1.0f - u) * c;
    }
  }
}

extern "C" void kernel_launch(void* const* d_in, const int* in_sizes, int n_in,
                              void* d_out, int out_size, void* d_ws, size_t ws_size,
                              hipStream_t stream) {
  const float* inp  = (const float*)d_in[0];
  const float* hx   = (const float*)d_in[1];
  const float* S0   = (const float*)d_in[2];
  const float* S1   = (const float*)d_in[3];
  const float* W    = (const float*)d_in[4];
  const float* bias = (const float*)d_in[5];
  const float* W2   = (const float*)d_in[6];
  const float* b2   = (const float*)d_in[7];
  float* out = (float*)d_out;

  char* ws = (char*)d_ws;
  const size_t XHB = (size_t)NN * XHC * sizeof(u16);
  const size_t XIB = (size_t)NN * XIC * sizeof(u16);
  u16* bufA = (u16*)(ws);              // xh0 -> xh'
  u16* bufB = (u16*)(ws + 1 * XHB);    // S0@x
  u16* bufC = (u16*)(ws + 2 * XHB);    // S0@S0@x
  u16* bufD = (u16*)(ws + 3 * XHB);    // S1@x
  u16* bufE = (u16*)(ws + 4 * XHB);    // S1@S1@x
  char* p = ws + 5 * XHB;
  u16* xi0 = (u16*)p;  p += XIB + 256;
  u16* yi1 = (u16*)p;  p += XIB + 256;
  u16* yi2 = (u16*)p;  p += XIB + 256;
  u16* yi3 = (u16*)p;  p += XIB + 256;
  u16* yi4 = (u16*)p;  p += XIB + 256;
  float* ubuf = (float*)p;             p += (size_t)NN * BB * UU * 4;
  int*   cols = (int*)p;               p += 2 * (size_t)NN * CAP * 4;
  float* vals = (float*)p;             p += 2 * (size_t)NN * CAP * 4;
  int*   nnzA = (int*)p;               p += 2 * (size_t)NN * 4;
  u16*   Wf   = (u16*)p;               p += (size_t)WF_G * 2;
  u16*   W2f  = (u16*)p;               p += (size_t)WF_C * 2;

  // fused prologue: prep_w | extract_csr | build_x0
  prologue<<<PW_BLK + 2048 + NN, 256, 0, stream>>>(
      W, W2, Wf, W2f, S0, S1, cols, vals, nnzA, inp, hx, xi0, bufA);

  // gconv1 hop1: both supports (shared source; xi tails)
  spmm_panel<<<dim3(10240, 2), 128, 0, stream>>>(cols, vals, nnzA,
      xi0, bufA, xi0, bufA, 0, yi1, bufB, yi3, bufD);
  // gconv1 hop2: both supports
  spmm_panel<<<dim3(10240, 2), 128, 0, stream>>>(cols, vals, nnzA,
      yi1, bufB, yi3, bufD, 0, yi2, bufC, yi4, bufE);

  // gate: writes xh' in place into bufA, u -> ubuf (xi frags read inline)
  gate_mfma<<<NN, 256, 0, stream>>>(xi0, yi1, yi2, yi3, yi4,
                                    bufA, bufB, bufC, bufD, bufE,
                                    Wf, bias, bufA, ubuf);

  // gconv2 on xh' (xi mats unchanged; no xi tail)
  spmm_panel<<<dim3(8192, 2), 128, 0, stream>>>(cols, vals, nnzA,
      xi0, bufA, xi0, bufA, 0, yi1, bufB, yi3, bufD);
  spmm_panel<<<dim3(8192, 2), 128, 0, stream>>>(cols, vals, nnzA,
      yi1, bufB, yi3, bufD, 0, yi2, bufC, yi4, bufE);

  // candidate + final combine
  cand_mfma<<<NN, 256, 0, stream>>>(xi0, yi1, yi2, yi3, yi4,
                                    bufA, bufB, bufC, bufD, bufE,
                                    W2f, b2, hx, ubuf, out);
}